// Round 7
// baseline (3063.501 us; speedup 1.0000x reference)
//
#include <hip/hip_runtime.h>
#include <math.h>

// RPNHead: conv3x3(512->512)+ReLU -> cls(9)/reg(36) 1x1 -> sigmoid/box-decode
// -> per-image exact top-1000 (by f64 score, index tie-break) -> greedy NMS
// -> [8,300,5] f32 output (kept-first stable order, zero-padded).
//
// Score/box pipeline in fp64 so top-k ordering and NMS decisions match a
// float64 numpy reference exactly (adjacent-score spacing ~5e-5..5e-8 >> f64
// noise ~1e-16; f32 would swap ranks -> wrong rows -> absmax ~1000).
//
// R2-R4: conv as implicit-GEMM on v_mfma_f64_16x16x4_f64; probe-decoded C/D
//        layout (gfx950 f64 MFMA mapping differs from CDNA2 docs).
// R5: f32 LDS, stride-80 pad, dbuf+T14, hoisted addressing. 2647us, 81%.
// R6: occupancy 2->3+ waves/SIMD (VGPR 112->64) + setprio. 2530us, 85.5%
//     MfmaUtil = 78% of the 78.6TF f64 matrix floor. Scheduling nearly done.
// R7: cut FLOPs 2.25x: Winograd F(2x2,3x3). x = A^T[ (G g G^T) . (B^T d B) ]A
//     -> 16 f64 GEMMs (512oc x 1024tiles x K=512) per image. All transforms
//     exact-ish in f64 (B^T in {0,+-1}, G in {0,1/2,1}): x error ~1e-13 <<
//     5e-8 decision margins. Needs ws >= 319.4MB (U 33.5 + V 67 + M 67 on
//     top of 151.6): kernel_launch picks Winograd iff ws_size fits, else the
//     proven R6 conv path (deterministic: ws_size is fixed).

typedef double f64x4 __attribute__((ext_vector_type(4)));
typedef double f64x2 __attribute__((ext_vector_type(2)));

#define BS 8
#define CIN 512
#define COUT 512
#define FH 64
#define FW 64
#define NA 9
#define NPIX (FH*FW)          // 4096
#define NANCH (NPIX*NA)       // 36864
#define NPAD 65536
#define KPRE 1000
#define KPOST 300

// ---- workspace layout (bytes) ----
#define OFF_X      0ull                                   // 8*512*4096 f64 = 134217728
#define OFF_SCORES (OFF_X + 134217728ull)                 // 8*36864 f64    = 2359296
#define OFF_BOXES  (OFF_SCORES + 2359296ull)              // 8*36864*4 f64  = 9437184
#define OFF_KEYS   (OFF_BOXES + 9437184ull)               // 8*65536 u64    = 4194304
#define OFF_BUF1   (OFF_KEYS + 4194304ull)                // 8*16*1024 u64  = 1048576
#define OFF_BUF2   (OFF_BUF1 + 1048576ull)                // 8*4*1024 u64   = 262144
#define OFF_SEL    (OFF_BUF2 + 262144ull)                 // 8*1024 i32     = 32768
#define OFF_KEEP   (OFF_SEL + 32768ull)                   // 8*1024 i32     = 32768
#define WS_NEEDED  (OFF_KEEP + 32768ull)                  // 151584768
// Winograd extension (only used when ws_size >= WS_WINO)
#define WOFF_U     WS_NEEDED                              // 16*512*512 f64  = 33554432
#define WOFF_V     (WOFF_U + 33554432ull)                 // 16*512*1024 f64 = 67108864
#define WOFF_M     (WOFF_V + 67108864ull)                 // 16*512*1024 f64 = 67108864
#define WS_WINO    (WOFF_M + 67108864ull)                 // 319356928

// =================== R6 direct-conv path (fallback) ==========================
#define SW_STRIDE 80
#define SW_WORDS  (36 * SW_STRIDE)
#define SI_RSTRIDE 80
#define SI_CSTRIDE 320
#define BUF_WORDS (SW_WORDS + 4 * SI_CSTRIDE)

__device__ __forceinline__ void conv_compute(
    const float* __restrict__ sWp, const float* __restrict__ sIp,
    const int* __restrict__ boff, f64x4 acc[2][4]) {
#pragma unroll
  for (int k0s = 0; k0s < 9; ++k0s) {
    double a0 = (double)sWp[k0s * 4 * SW_STRIDE];
    double a1 = (double)sWp[k0s * 4 * SW_STRIDE + 16];
    const float* bp = sIp + boff[k0s];
    double b0 = (double)bp[0];
    double b1 = (double)bp[16];
    double b2 = (double)bp[32];
    double b3 = (double)bp[48];
    acc[0][0] = __builtin_amdgcn_mfma_f64_16x16x4f64(a0, b0, acc[0][0], 0, 0, 0);
    acc[0][1] = __builtin_amdgcn_mfma_f64_16x16x4f64(a0, b1, acc[0][1], 0, 0, 0);
    acc[0][2] = __builtin_amdgcn_mfma_f64_16x16x4f64(a0, b2, acc[0][2], 0, 0, 0);
    acc[0][3] = __builtin_amdgcn_mfma_f64_16x16x4f64(a0, b3, acc[0][3], 0, 0, 0);
    acc[1][0] = __builtin_amdgcn_mfma_f64_16x16x4f64(a1, b0, acc[1][0], 0, 0, 0);
    acc[1][1] = __builtin_amdgcn_mfma_f64_16x16x4f64(a1, b1, acc[1][1], 0, 0, 0);
    acc[1][2] = __builtin_amdgcn_mfma_f64_16x16x4f64(a1, b2, acc[1][2], 0, 0, 0);
    acc[1][3] = __builtin_amdgcn_mfma_f64_16x16x4f64(a1, b3, acc[1][3], 0, 0, 0);
  }
}

__global__ __launch_bounds__(256, 3) void conv_mfma_kernel(
    const float* __restrict__ fm, const float* __restrict__ W,
    const float* __restrict__ bias, double* __restrict__ x) {
  __shared__ float sbuf[2 * BUF_WORDS];
  const int ocb = blockIdx.x, rp = blockIdx.y, b = blockIdx.z;
  const int h0 = rp * 2;
  const int oc0 = ocb * 64;
  const int tid = threadIdx.x;
  const int wid = tid >> 6, l = tid & 63;
  const int q = l >> 4, r16 = l & 15;
  const int wm = wid >> 1, wn = wid & 1;

  const int wo = tid >> 2, wseg = tid & 3;
  const float* wbase = W + (size_t)(oc0 + wo) * 4608 + wseg * 9;
  const int wlds0 = (wseg * 9) * SW_STRIDE + wo;

  const float* fmb = fm + (size_t)b * CIN * NPIX;
  int ioff[5];
  int idls[5];
  bool sact[5], lact[5];
#pragma unroll
  for (int s = 0; s < 5; ++s) {
    int li = tid + 256 * s;
    sact[s] = li < 1056;
    int li_c = sact[s] ? li : 0;
    int c = li_c / 264, rem = li_c % 264, r = rem / 66, col = rem % 66;
    int gy = h0 - 1 + r, gx = col - 1;
    lact[s] = sact[s] && gy >= 0 && gy < FH && gx >= 0 && gx < FW;
    ioff[s] = lact[s] ? (c * NPIX + gy * FW + gx) : 0;
    idls[s] = SW_WORDS + c * SI_CSTRIDE + r * SI_RSTRIDE + col;
  }

  const int apos = q * SW_STRIDE + wm * 32 + r16;
  const int ipos = SW_WORDS + wn * SI_RSTRIDE + r16;
  int boff[9];
#pragma unroll
  for (int k0s = 0; k0s < 9; ++k0s) {
    int k = k0s * 4 + q;
    int c = k / 9, t = k - 9 * c;
    int dy = t / 3, dx = t - 3 * dy;
    boff[k0s] = c * SI_CSTRIDE + dy * SI_RSTRIDE + dx;
  }

  f64x4 acc[2][4];
#pragma unroll
  for (int tm = 0; tm < 2; ++tm)
#pragma unroll
    for (int tn = 0; tn < 4; ++tn)
#pragma unroll
      for (int v = 0; v < 4; ++v) acc[tm][tn][v] = 0.0;

  float wreg[9], ireg[5];

#define LOAD_REGS(t) do {                                            \
    const int cc_ = 4 * (t);                                         \
    _Pragma("unroll")                                                \
    for (int j = 0; j < 9; ++j) wreg[j] = wbase[cc_ * 9 + j];        \
    _Pragma("unroll")                                                \
    for (int s = 0; s < 5; ++s)                                      \
      ireg[s] = lact[s] ? fmb[(size_t)(ioff[s] + cc_ * NPIX)] : 0.f; \
  } while (0)

#define WRITE_LDS(base) do {                                         \
    _Pragma("unroll")                                                \
    for (int j = 0; j < 9; ++j) (base)[wlds0 + j * SW_STRIDE] = wreg[j]; \
    _Pragma("unroll")                                                \
    for (int s = 0; s < 5; ++s)                                      \
      if (sact[s]) (base)[idls[s]] = ireg[s];                        \
  } while (0)

  float* buf0 = sbuf;
  float* buf1 = sbuf + BUF_WORDS;

  LOAD_REGS(0);
  WRITE_LDS(buf0);
  __syncthreads();

  for (int tt = 0; tt < 64; ++tt) {
    const int t1 = 2 * tt + 1;
    LOAD_REGS(t1);
    __builtin_amdgcn_s_setprio(1);
    conv_compute(buf0 + apos, buf0 + ipos, boff, acc);
    __builtin_amdgcn_s_setprio(0);
    WRITE_LDS(buf1);
    __syncthreads();
    const int t2 = (t1 + 1 < 128) ? t1 + 1 : 127;
    LOAD_REGS(t2);
    __builtin_amdgcn_s_setprio(1);
    conv_compute(buf1 + apos, buf1 + ipos, boff, acc);
    __builtin_amdgcn_s_setprio(0);
    WRITE_LDS(buf0);
    __syncthreads();
  }

  int prow[4], pcol[4];
  {
    f64x4 probe = {0.0, 0.0, 0.0, 0.0};
    double pa = (q == 0) ? (double)r16 : ((q == 1) ? 1.0 : 0.0);
    double pb = (q == 0) ? 1.0 : ((q == 1) ? (double)(16 * r16) : 0.0);
    probe = __builtin_amdgcn_mfma_f64_16x16x4f64(pa, pb, probe, 0, 0, 0);
#pragma unroll
    for (int v = 0; v < 4; ++v) {
      int val = (int)(probe[v] + 0.5);
      prow[v] = val & 15;
      pcol[v] = (val >> 4) & 15;
    }
  }

#pragma unroll
  for (int tm = 0; tm < 2; ++tm) {
#pragma unroll
    for (int v = 0; v < 4; ++v) {
      const int oc = oc0 + wm * 32 + tm * 16 + prow[v];
      const double bv = (double)bias[oc];
      const int h = h0 + wn;
#pragma unroll
      for (int tn = 0; tn < 4; ++tn) {
        const int w = tn * 16 + pcol[v];
        double val = acc[tm][tn][v] + bv;
        val = val > 0.0 ? val : 0.0;
        x[(size_t)(b * COUT + oc) * NPIX + h * FW + w] = val;
      }
    }
  }
#undef LOAD_REGS
#undef WRITE_LDS
}

// =================== Winograd F(2x2,3x3) path ================================
// U[pos][c][oc] = (G g G^T), G = [[1,0,0],[.5,.5,.5],[.5,-.5,.5],[0,0,1]]
__global__ __launch_bounds__(256) void wino_wt_kernel(
    const float* __restrict__ W, double* __restrict__ U) {
  const int id = blockIdx.x * 256 + threadIdx.x;   // 262144
  const int oc = id >> 9, c = id & 511;
  const float* g = W + (size_t)(oc * CIN + c) * 9;
  double g0[3], g1[3], g2[3];
#pragma unroll
  for (int j = 0; j < 3; ++j) {
    g0[j] = (double)g[j];
    g1[j] = (double)g[3 + j];
    g2[j] = (double)g[6 + j];
  }
  double T[4][3];
#pragma unroll
  for (int j = 0; j < 3; ++j) {
    T[0][j] = g0[j];
    T[1][j] = 0.5 * (g0[j] + g1[j] + g2[j]);
    T[2][j] = 0.5 * (g0[j] - g1[j] + g2[j]);
    T[3][j] = g2[j];
  }
  double* Ub = U + (size_t)c * 512 + oc;   // + pos*262144
#pragma unroll
  for (int xi = 0; xi < 4; ++xi) {
    double u0 = T[xi][0];
    double u1 = 0.5 * (T[xi][0] + T[xi][1] + T[xi][2]);
    double u2 = 0.5 * (T[xi][0] - T[xi][1] + T[xi][2]);
    double u3 = T[xi][2];
    Ub[(size_t)(xi * 4 + 0) * 262144] = u0;
    Ub[(size_t)(xi * 4 + 1) * 262144] = u1;
    Ub[(size_t)(xi * 4 + 2) * 262144] = u2;
    Ub[(size_t)(xi * 4 + 3) * 262144] = u3;
  }
}

// V[pos][c][tile] = B^T d B per (c, 2x2-output tile) of image b.
// B^T = [[1,0,-1,0],[0,1,1,0],[0,-1,1,0],[0,1,0,-1]]
__global__ __launch_bounds__(256) void wino_in_kernel(
    const float* __restrict__ fm, double* __restrict__ V, int b) {
  const int id = blockIdx.x * 256 + threadIdx.x;   // 524288
  const int c = id >> 10, tyx = id & 1023;
  const int ty = tyx >> 5, tx = tyx & 31;
  const float* src = fm + (size_t)(b * CIN + c) * NPIX;
  const int y0 = 2 * ty - 1, x0 = 2 * tx - 1;
  double d[4][4];
#pragma unroll
  for (int r = 0; r < 4; ++r) {
    int y = y0 + r;
#pragma unroll
    for (int s = 0; s < 4; ++s) {
      int xx = x0 + s;
      d[r][s] = (y >= 0 && y < FH && xx >= 0 && xx < FW)
                    ? (double)src[y * FW + xx] : 0.0;
    }
  }
  double Z[4][4];
#pragma unroll
  for (int s = 0; s < 4; ++s) {
    Z[0][s] = d[0][s] - d[2][s];
    Z[1][s] = d[1][s] + d[2][s];
    Z[2][s] = d[2][s] - d[1][s];
    Z[3][s] = d[1][s] - d[3][s];
  }
  double* Vb = V + (size_t)c * 1024 + tyx;   // + pos*524288
#pragma unroll
  for (int xi = 0; xi < 4; ++xi) {
    double v0 = Z[xi][0] - Z[xi][2];
    double v1 = Z[xi][1] + Z[xi][2];
    double v2 = Z[xi][2] - Z[xi][1];
    double v3 = Z[xi][1] - Z[xi][3];
    Vb[(size_t)(xi * 4 + 0) * 524288] = v0;
    Vb[(size_t)(xi * 4 + 1) * 524288] = v1;
    Vb[(size_t)(xi * 4 + 2) * 524288] = v2;
    Vb[(size_t)(xi * 4 + 3) * 524288] = v3;
  }
}

// M[pos] = U[pos] (512oc x 512c) * V[pos] (512c x 1024 tiles), f64 MFMA.
// Same feed pattern + probe-decoded D mapping as conv_mfma_kernel.
// LDS (f64): sU [8][72] then sV [8][136]; double-buffered; chunk KC=8.
#define WSU_STRIDE 72
#define WSV_STRIDE 136
#define WSU_WORDS  (8 * WSU_STRIDE)              // 576
#define WBUF_WORDS (WSU_WORDS + 8 * WSV_STRIDE)  // 1664 f64 = 13312 B

__device__ __forceinline__ void wino_compute(
    const double* __restrict__ sA, const double* __restrict__ sB,
    f64x4 acc[2][4]) {
#pragma unroll
  for (int kg = 0; kg < 2; ++kg) {
    double a0 = sA[kg * 4 * WSU_STRIDE];
    double a1 = sA[kg * 4 * WSU_STRIDE + 16];
    const double* bp = sB + kg * 4 * WSV_STRIDE;
    double b0 = bp[0];
    double b1 = bp[16];
    double b2 = bp[32];
    double b3 = bp[48];
    acc[0][0] = __builtin_amdgcn_mfma_f64_16x16x4f64(a0, b0, acc[0][0], 0, 0, 0);
    acc[0][1] = __builtin_amdgcn_mfma_f64_16x16x4f64(a0, b1, acc[0][1], 0, 0, 0);
    acc[0][2] = __builtin_amdgcn_mfma_f64_16x16x4f64(a0, b2, acc[0][2], 0, 0, 0);
    acc[0][3] = __builtin_amdgcn_mfma_f64_16x16x4f64(a0, b3, acc[0][3], 0, 0, 0);
    acc[1][0] = __builtin_amdgcn_mfma_f64_16x16x4f64(a1, b0, acc[1][0], 0, 0, 0);
    acc[1][1] = __builtin_amdgcn_mfma_f64_16x16x4f64(a1, b1, acc[1][1], 0, 0, 0);
    acc[1][2] = __builtin_amdgcn_mfma_f64_16x16x4f64(a1, b2, acc[1][2], 0, 0, 0);
    acc[1][3] = __builtin_amdgcn_mfma_f64_16x16x4f64(a1, b3, acc[1][3], 0, 0, 0);
  }
}

__global__ __launch_bounds__(256, 3) void wino_gemm_kernel(
    const double* __restrict__ U, const double* __restrict__ V,
    double* __restrict__ M) {
  __shared__ double sbuf[2 * WBUF_WORDS];
  const int ocb = blockIdx.x, tb = blockIdx.y, pos = blockIdx.z;
  const int oc0 = ocb * 64, t0 = tb * 128;
  const int tid = threadIdx.x;
  const int wid = tid >> 6, l = tid & 63;
  const int q = l >> 4, r16 = l & 15;
  const int wm = wid >> 1, wn = wid & 1;   // 2(M) x 2(N) waves

  // staging maps (loop-invariant)
  const int ka = tid >> 5;                 // 0..7
  const int oc2 = (tid & 31) * 2;          // A: 2 f64/thread
  const int t4 = (tid & 31) * 4;           // B: 4 f64/thread
  const double* uSrc = U + (size_t)pos * 262144 + (size_t)ka * 512 + oc0 + oc2;
  const double* vSrc = V + (size_t)pos * 524288 + (size_t)ka * 1024 + t0 + t4;
  const int ua_lds = ka * WSU_STRIDE + oc2;
  const int vb_lds = WSU_WORDS + ka * WSV_STRIDE + t4;

  // fragment read bases
  const int apos = q * WSU_STRIDE + wm * 32 + r16;
  const int bpos = WSU_WORDS + q * WSV_STRIDE + wn * 64 + r16;

  f64x4 acc[2][4];
#pragma unroll
  for (int tm = 0; tm < 2; ++tm)
#pragma unroll
    for (int tn = 0; tn < 4; ++tn)
#pragma unroll
      for (int v = 0; v < 4; ++v) acc[tm][tn][v] = 0.0;

  f64x2 ra, rb0, rb1;

#define WLOAD(t) do {                                                  \
    const size_t cc_ = 8 * (size_t)(t);                                \
    ra  = *(const f64x2*)(uSrc + cc_ * 512);                           \
    rb0 = *(const f64x2*)(vSrc + cc_ * 1024);                          \
    rb1 = *(const f64x2*)(vSrc + cc_ * 1024 + 2);                      \
  } while (0)

#define WSTORE(base) do {                                              \
    (base)[ua_lds] = ra[0]; (base)[ua_lds + 1] = ra[1];                \
    (base)[vb_lds] = rb0[0]; (base)[vb_lds + 1] = rb0[1];              \
    (base)[vb_lds + 2] = rb1[0]; (base)[vb_lds + 3] = rb1[1];          \
  } while (0)

  double* buf0 = sbuf;
  double* buf1 = sbuf + WBUF_WORDS;

  WLOAD(0);
  WSTORE(buf0);
  __syncthreads();

  for (int tt = 0; tt < 32; ++tt) {
    const int t1 = 2 * tt + 1;
    WLOAD(t1);
    __builtin_amdgcn_s_setprio(1);
    wino_compute(buf0 + apos, buf0 + bpos, acc);
    __builtin_amdgcn_s_setprio(0);
    WSTORE(buf1);
    __syncthreads();
    const int t2 = (t1 + 1 < 64) ? t1 + 1 : 63;
    WLOAD(t2);
    __builtin_amdgcn_s_setprio(1);
    wino_compute(buf1 + apos, buf1 + bpos, acc);
    __builtin_amdgcn_s_setprio(0);
    WSTORE(buf0);
    __syncthreads();
  }

  // probe-decoded D mapping (same as conv path)
  int prow[4], pcol[4];
  {
    f64x4 probe = {0.0, 0.0, 0.0, 0.0};
    double pa = (q == 0) ? (double)r16 : ((q == 1) ? 1.0 : 0.0);
    double pb = (q == 0) ? 1.0 : ((q == 1) ? (double)(16 * r16) : 0.0);
    probe = __builtin_amdgcn_mfma_f64_16x16x4f64(pa, pb, probe, 0, 0, 0);
#pragma unroll
    for (int v = 0; v < 4; ++v) {
      int val = (int)(probe[v] + 0.5);
      prow[v] = val & 15;
      pcol[v] = (val >> 4) & 15;
    }
  }

#pragma unroll
  for (int tm = 0; tm < 2; ++tm) {
#pragma unroll
    for (int v = 0; v < 4; ++v) {
      const int oc = oc0 + wm * 32 + tm * 16 + prow[v];
#pragma unroll
      for (int tn = 0; tn < 4; ++tn) {
        const int col = wn * 64 + tn * 16 + pcol[v];
        M[(size_t)pos * 524288 + (size_t)oc * 1024 + t0 + col] = acc[tm][tn][v];
      }
    }
  }
#undef WLOAD
#undef WSTORE
}

// x[b][oc][2ty+i][2tx+j] = relu( (A^T m A)[i][j] + bias ), A^T = [[1,1,1,0],[0,1,-1,-1]]
__global__ __launch_bounds__(256) void wino_out_kernel(
    const double* __restrict__ M, const float* __restrict__ bias,
    double* __restrict__ x, int b) {
  const int id = blockIdx.x * 256 + threadIdx.x;   // 524288
  const int oc = id >> 10, tyx = id & 1023;
  const int ty = tyx >> 5, tx = tyx & 31;
  double m[4][4];
#pragma unroll
  for (int xi = 0; xi < 4; ++xi)
#pragma unroll
    for (int nu = 0; nu < 4; ++nu)
      m[xi][nu] = M[(size_t)(xi * 4 + nu) * 524288 + (size_t)oc * 1024 + tyx];
  double P[2][4];
#pragma unroll
  for (int nu = 0; nu < 4; ++nu) {
    P[0][nu] = m[0][nu] + m[1][nu] + m[2][nu];
    P[1][nu] = m[1][nu] - m[2][nu] - m[3][nu];
  }
  const double bv = (double)bias[oc];
  double* xb = x + (size_t)(b * COUT + oc) * NPIX + (2 * ty) * FW + 2 * tx;
#pragma unroll
  for (int i = 0; i < 2; ++i) {
    double y0 = P[i][0] + P[i][1] + P[i][2] + bv;
    double y1 = P[i][1] - P[i][2] - P[i][3] + bv;
    y0 = y0 > 0.0 ? y0 : 0.0;
    y1 = y1 > 0.0 ? y1 : 0.0;
    xb[i * FW] = y0;
    xb[i * FW + 1] = y1;
  }
}

// ---------------- heads: 45 logits/pixel -> scores, boxes, sort keys ----------
__global__ __launch_bounds__(256) void heads_kernel(
    const double* __restrict__ x, const float* __restrict__ cls_w,
    const float* __restrict__ cls_b, const float* __restrict__ reg_w,
    const float* __restrict__ reg_b, const int* __restrict__ img_h,
    const int* __restrict__ img_w, double* __restrict__ scores,
    double* __restrict__ boxes, unsigned long long* __restrict__ keys) {
  __shared__ double sx[4096];
  __shared__ double swl[2880];
  const int b = blockIdx.x >> 6;
  const int ptile = blockIdx.x & 63;
  const int tx = threadIdx.x, ty = threadIdx.y;
  const int tid = ty * 64 + tx;

  double acc[12];
#pragma unroll
  for (int j = 0; j < 12; ++j) acc[j] = 0.0;

  for (int cc = 0; cc < CIN; cc += 64) {
    for (int li = tid; li < 4096; li += 256) {
      int ci = li >> 6, px = li & 63;
      sx[li] = x[((long)b * CIN + cc + ci) * NPIX + ptile * 64 + px];
    }
    for (int li = tid; li < 2880; li += 256) {
      int o = li >> 6, ci = li & 63;
      float wv = (o < 9) ? cls_w[o * CIN + cc + ci] : reg_w[(o - 9) * CIN + cc + ci];
      swl[li] = (double)wv;
    }
    __syncthreads();
#pragma unroll 4
    for (int ci = 0; ci < 64; ++ci) {
      double xv = sx[ci * 64 + tx];
#pragma unroll
      for (int j = 0; j < 12; ++j) {
        int o = ty + 4 * j;
        if (o < 45) acc[j] += swl[o * 64 + ci] * xv;
      }
    }
    __syncthreads();
  }

#pragma unroll
  for (int j = 0; j < 12; ++j) {
    int o = ty + 4 * j;
    if (o < 45) {
      double bv = (o < 9) ? (double)cls_b[o] : (double)reg_b[o - 9];
      swl[o * 64 + tx] = acc[j] + bv;
    }
  }
  __syncthreads();

  const double ih = (double)img_h[0], iw = (double)img_w[0];
  const double sth = ih / (double)FH, stw = iw / (double)FW;
  const double ratios[3] = {0.5, 1.0, 2.0};
  const double sizes[3] = {128.0, 256.0, 512.0};

  for (int it = tid; it < 576; it += 256) {
    int px = it / 9, a = it % 9;
    int p = ptile * 64 + px;
    int hh = p >> 6, ww = p & 63;
    double z = swl[a * 64 + px];
    double score = 1.0 / (1.0 + exp(-z));
    double d0 = swl[(9 + a * 4 + 0) * 64 + px];
    double d1 = swl[(9 + a * 4 + 1) * 64 + px];
    double d2 = swl[(9 + a * 4 + 2) * 64 + px];
    double d3 = swl[(9 + a * 4 + 3) * 64 + px];
    double ratio = ratios[a / 3], size = sizes[a % 3];
    double hr = sqrt(ratio), wr = 1.0 / hr;
    double wsz = wr * size, hsz = hr * size;
    double sxc = (double)ww * stw, syc = (double)hh * sth;
    double ax0 = sxc - wsz * 0.5, ax1 = sxc + wsz * 0.5;
    double ay0 = syc - hsz * 0.5, ay1 = syc + hsz * 0.5;
    double aw = ax1 - ax0, ah = ay1 - ay0;
    double acx = ax0 + 0.5 * aw, acy = ay0 + 0.5 * ah;
    double pcx = d0 * aw + acx, pcy = d1 * ah + acy;
    double pw = exp(d2) * aw, ph = exp(d3) * ah;
    double bx0 = pcx - 0.5 * pw, by0 = pcy - 0.5 * ph;
    double bx1 = pcx + 0.5 * pw, by1 = pcy + 0.5 * ph;
    bx0 = fmin(fmax(bx0, 0.0), iw); bx1 = fmin(fmax(bx1, 0.0), iw);
    by0 = fmin(fmax(by0, 0.0), ih); by1 = fmin(fmax(by1, 0.0), ih);
    long n = (long)p * 9 + a;
    long base = (long)b * NANCH + n;
    boxes[base * 4 + 0] = bx0; boxes[base * 4 + 1] = by0;
    boxes[base * 4 + 2] = bx1; boxes[base * 4 + 3] = by1;
    scores[base] = score;
    unsigned long long bits = (unsigned long long)__double_as_longlong(score);
    keys[(long)b * NPAD + n] =
        ~((bits & 0xFFFFFFFFFFFF0000ull) | (0xFFFFull - (unsigned long long)n));
  }
}

// ---------------- bitonic sort of 4096 u64 in LDS (ascending) ----------------
__device__ inline void bitonic4096(unsigned long long* s, int tid) {
  for (int k = 2; k <= 4096; k <<= 1) {
    for (int j = k >> 1; j > 0; j >>= 1) {
#pragma unroll 2
      for (int t = tid; t < 2048; t += 1024) {
        int i = ((t & ~(j - 1)) << 1) | (t & (j - 1));
        int p = i | j;
        bool up = ((i & k) == 0);
        unsigned long long a = s[i], c = s[p];
        if ((a > c) == up) { s[i] = c; s[p] = a; }
      }
      __syncthreads();
    }
  }
}

__global__ __launch_bounds__(1024) void sort_topk_kernel(
    const unsigned long long* __restrict__ in, unsigned long long* __restrict__ out,
    long in_stride, long out_stride) {
  __shared__ unsigned long long s[4096];
  const int b = blockIdx.y, q = blockIdx.x, tid = threadIdx.x;
  const unsigned long long* ip = in + (long)b * in_stride + (long)q * 4096;
#pragma unroll 4
  for (int l = tid; l < 4096; l += 1024) s[l] = ip[l];
  __syncthreads();
  bitonic4096(s, tid);
  unsigned long long* op = out + (long)b * out_stride + (long)q * 1024;
  op[tid] = s[tid];
}

__global__ __launch_bounds__(1024) void sort_final_kernel(
    const unsigned long long* __restrict__ in, int* __restrict__ sel) {
  __shared__ unsigned long long s[4096];
  const int b = blockIdx.x, tid = threadIdx.x;
  const unsigned long long* ip = in + (long)b * 4096;
#pragma unroll 4
  for (int l = tid; l < 4096; l += 1024) s[l] = ip[l];
  __syncthreads();
  bitonic4096(s, tid);
  if (tid < KPRE) sel[b * 1024 + tid] = (int)(s[tid] & 0xFFFFull);
}

// ---------------- greedy sequential NMS, f64, one block per image ------------
__global__ __launch_bounds__(256) void nms_kernel(
    const double* __restrict__ boxes, const int* __restrict__ sel,
    int* __restrict__ keep) {
  __shared__ double X0[KPRE], Y0[KPRE], X1[KPRE], Y1[KPRE], AR[KPRE];
  __shared__ int KP[KPRE];
  const int b = blockIdx.x, tid = threadIdx.x;
  for (int r = tid; r < KPRE; r += 256) {
    int n = sel[b * 1024 + r];
    const double* bp = boxes + ((long)b * NANCH + n) * 4;
    double x0 = bp[0], y0 = bp[1], x1 = bp[2], y1 = bp[3];
    X0[r] = x0; Y0[r] = y0; X1[r] = x1; Y1[r] = y1;
    AR[r] = (x1 - x0) * (y1 - y0);
    KP[r] = 1;
  }
  __syncthreads();
  for (int i = 0; i < KPRE - 1; ++i) {
    if (KP[i]) {
      double xi0 = X0[i], yi0 = Y0[i], xi1 = X1[i], yi1 = Y1[i], ai = AR[i];
      for (int j = i + 1 + tid; j < KPRE; j += 256) {
        double lx = fmax(xi0, X0[j]), ly = fmax(yi0, Y0[j]);
        double rx = fmin(xi1, X1[j]), ry = fmin(yi1, Y1[j]);
        double w = rx - lx; w = fmax(w, 0.0);
        double h = ry - ly; h = fmax(h, 0.0);
        double inter = w * h;
        double iou = inter / (ai + AR[j] - inter + 1e-9);
        if (iou > 0.7) KP[j] = 0;
      }
    }
    __syncthreads();
  }
  for (int r = tid; r < KPRE; r += 256) keep[b * 1024 + r] = KP[r];
}

// ---------------- output: kept-first stable order, zero pad ------------------
__global__ __launch_bounds__(1024) void out_kernel(
    const double* __restrict__ boxes, const double* __restrict__ scores,
    const int* __restrict__ sel, const int* __restrict__ keep,
    float* __restrict__ out) {
  const int b = blockIdx.x, tid = threadIdx.x;
  int kv = (tid < KPRE) ? keep[b * 1024 + tid] : 0;
  unsigned long long m = __ballot(kv != 0);
  int lane = tid & 63, wid = tid >> 6;
  __shared__ int wcnt[16], woff[16], tot;
  if (lane == 0) wcnt[wid] = __popcll(m);
  __syncthreads();
  if (tid == 0) {
    int s = 0;
    for (int w2 = 0; w2 < 16; ++w2) { woff[w2] = s; s += wcnt[w2]; }
    tot = s;
  }
  __syncthreads();
  int before = __popcll(m & ((1ull << lane) - 1ull));
  int pref = woff[wid] + before;
  if (tid < KPRE) {
    int pos = kv ? pref : (tot + (tid - pref));
    if (pos < KPOST) {
      float* o = out + ((long)b * KPOST + pos) * 5;
      if (kv) {
        int n = sel[b * 1024 + tid];
        const double* bp = boxes + ((long)b * NANCH + n) * 4;
        o[0] = (float)bp[0]; o[1] = (float)bp[1];
        o[2] = (float)bp[2]; o[3] = (float)bp[3];
        o[4] = (float)scores[(long)b * NANCH + n];
      } else {
        o[0] = 0.f; o[1] = 0.f; o[2] = 0.f; o[3] = 0.f; o[4] = 0.f;
      }
    }
  }
}

extern "C" void kernel_launch(void* const* d_in, const int* in_sizes, int n_in,
                              void* d_out, int out_size, void* d_ws, size_t ws_size,
                              hipStream_t stream) {
  const float* fm     = (const float*)d_in[0];
  const float* base_w = (const float*)d_in[1];
  const float* base_b = (const float*)d_in[2];
  const float* cls_w  = (const float*)d_in[3];
  const float* cls_b  = (const float*)d_in[4];
  const float* reg_w  = (const float*)d_in[5];
  const float* reg_b  = (const float*)d_in[6];
  const int* img_h    = (const int*)d_in[7];
  const int* img_w    = (const int*)d_in[8];
  float* out          = (float*)d_out;

  if (ws_size < WS_NEEDED) return;  // visible failure rather than corruption

  char* ws = (char*)d_ws;
  double* x                 = (double*)(ws + OFF_X);
  double* scores            = (double*)(ws + OFF_SCORES);
  double* boxes             = (double*)(ws + OFF_BOXES);
  unsigned long long* keys  = (unsigned long long*)(ws + OFF_KEYS);
  unsigned long long* buf1  = (unsigned long long*)(ws + OFF_BUF1);
  unsigned long long* buf2  = (unsigned long long*)(ws + OFF_BUF2);
  int* sel                  = (int*)(ws + OFF_SEL);
  int* keep                 = (int*)(ws + OFF_KEEP);

  // pad keys (anchors 36864..65535) and buf1 (chunks 9..15) with worst key
  hipMemsetAsync(ws + OFF_KEYS, 0xFF, 4194304ull + 1048576ull, stream);

  if (ws_size >= WS_WINO) {
    // Winograd conv: 2.25x fewer matrix FLOPs
    double* U = (double*)(ws + WOFF_U);
    double* V = (double*)(ws + WOFF_V);
    double* M = (double*)(ws + WOFF_M);
    wino_wt_kernel<<<dim3(1024), dim3(256), 0, stream>>>(base_w, U);
    for (int b = 0; b < BS; ++b) {
      wino_in_kernel<<<dim3(2048), dim3(256), 0, stream>>>(fm, V, b);
      wino_gemm_kernel<<<dim3(8, 8, 16), dim3(256), 0, stream>>>(U, V, M);
      wino_out_kernel<<<dim3(2048), dim3(256), 0, stream>>>(M, base_b, x, b);
    }
  } else {
    // direct implicit-GEMM conv (R6 path)
    conv_mfma_kernel<<<dim3(8, 32, 8), dim3(256), 0, stream>>>(fm, base_w, base_b, x);
  }

  heads_kernel<<<dim3(512), dim3(64, 4), 0, stream>>>(
      x, cls_w, cls_b, reg_w, reg_b, img_h, img_w, scores, boxes, keys);
  sort_topk_kernel<<<dim3(9, 8), dim3(1024), 0, stream>>>(keys, buf1, 65536, 16384);
  sort_topk_kernel<<<dim3(4, 8), dim3(1024), 0, stream>>>(buf1, buf2, 16384, 4096);
  sort_final_kernel<<<dim3(8), dim3(1024), 0, stream>>>(buf2, sel);
  nms_kernel<<<dim3(8), dim3(256), 0, stream>>>(boxes, sel, keep);
  out_kernel<<<dim3(8), dim3(1024), 0, stream>>>(boxes, scores, sel, keep, out);
}

// Round 8
// 2272.235 us; speedup vs baseline: 1.3482x; 1.3482x over previous
//
#include <hip/hip_runtime.h>
#include <math.h>

// RPNHead: conv3x3(512->512)+ReLU -> cls(9)/reg(36) 1x1 -> sigmoid/box-decode
// -> per-image exact top-1000 (by f64 score, index tie-break) -> greedy NMS
// -> [8,300,5] f32 output (kept-first stable order, zero-padded).
//
// Score/box pipeline in fp64 so top-k ordering and NMS decisions match a
// float64 numpy reference exactly (adjacent-score spacing ~5e-5..5e-8 >> f64
// noise ~1e-16; f32 would swap ranks -> wrong rows -> absmax ~1000).
//
// R2-R4: conv as implicit-GEMM on v_mfma_f64_16x16x4_f64; probe-decoded C/D
//        layout (gfx950 f64 MFMA mapping differs from CDNA2 docs).
// R5: f32 LDS, stride-80 pad, dbuf+T14, hoisted addressing. 2647us, 81%.
// R6: occupancy 2->3+ waves/SIMD + setprio. conv 2530us, MfmaUtil 85.5%.
// R7: Winograd F(2x2,3x3) full-image path (needs 319.4MB ws) -- never ran:
//     counters showed conv_mfma_kernel => ws_size < 319.4MB. Learned bound.
// R8: tile-chunked Winograd: V/M hold T tiles (T=512 -> 33.5MB each),
//     WS_WINO_HALF = 252.2MB. Tiers: full(1024) / half(512) / direct.
//     Whichever path runs brackets ws_size. GEMM reuses the R6-verified
//     feed + probe-decoded D epilogue; transforms are Lavin F(2,3)
//     correlation form (matches the verified direct conv's convention).

typedef double f64x4 __attribute__((ext_vector_type(4)));
typedef double f64x2 __attribute__((ext_vector_type(2)));

#define BS 8
#define CIN 512
#define COUT 512
#define FH 64
#define FW 64
#define NA 9
#define NPIX (FH*FW)          // 4096
#define NANCH (NPIX*NA)       // 36864
#define NPAD 65536
#define KPRE 1000
#define KPOST 300

// ---- workspace layout (bytes) ----
#define OFF_X      0ull                                   // 8*512*4096 f64 = 134217728
#define OFF_SCORES (OFF_X + 134217728ull)                 // 8*36864 f64    = 2359296
#define OFF_BOXES  (OFF_SCORES + 2359296ull)              // 8*36864*4 f64  = 9437184
#define OFF_KEYS   (OFF_BOXES + 9437184ull)               // 8*65536 u64    = 4194304
#define OFF_BUF1   (OFF_KEYS + 4194304ull)                // 8*16*1024 u64  = 1048576
#define OFF_BUF2   (OFF_BUF1 + 1048576ull)                // 8*4*1024 u64   = 262144
#define OFF_SEL    (OFF_BUF2 + 262144ull)                 // 8*1024 i32     = 32768
#define OFF_KEEP   (OFF_SEL + 32768ull)                   // 8*1024 i32     = 32768
#define WS_NEEDED  (OFF_KEEP + 32768ull)                  // 151584768
// Winograd extension
#define WOFF_U        WS_NEEDED                           // 16*512*512 f64 = 33554432
#define WOFF_V        (WOFF_U + 33554432ull)
#define WS_WINO_FULL  (WOFF_V + 67108864ull + 67108864ull)  // 319356928
#define WS_WINO_HALF  (WOFF_V + 33554432ull + 33554432ull)  // 252248064

// =================== R6 direct-conv path (fallback) ==========================
#define SW_STRIDE 80
#define SW_WORDS  (36 * SW_STRIDE)
#define SI_RSTRIDE 80
#define SI_CSTRIDE 320
#define BUF_WORDS (SW_WORDS + 4 * SI_CSTRIDE)

__device__ __forceinline__ void conv_compute(
    const float* __restrict__ sWp, const float* __restrict__ sIp,
    const int* __restrict__ boff, f64x4 acc[2][4]) {
#pragma unroll
  for (int k0s = 0; k0s < 9; ++k0s) {
    double a0 = (double)sWp[k0s * 4 * SW_STRIDE];
    double a1 = (double)sWp[k0s * 4 * SW_STRIDE + 16];
    const float* bp = sIp + boff[k0s];
    double b0 = (double)bp[0];
    double b1 = (double)bp[16];
    double b2 = (double)bp[32];
    double b3 = (double)bp[48];
    acc[0][0] = __builtin_amdgcn_mfma_f64_16x16x4f64(a0, b0, acc[0][0], 0, 0, 0);
    acc[0][1] = __builtin_amdgcn_mfma_f64_16x16x4f64(a0, b1, acc[0][1], 0, 0, 0);
    acc[0][2] = __builtin_amdgcn_mfma_f64_16x16x4f64(a0, b2, acc[0][2], 0, 0, 0);
    acc[0][3] = __builtin_amdgcn_mfma_f64_16x16x4f64(a0, b3, acc[0][3], 0, 0, 0);
    acc[1][0] = __builtin_amdgcn_mfma_f64_16x16x4f64(a1, b0, acc[1][0], 0, 0, 0);
    acc[1][1] = __builtin_amdgcn_mfma_f64_16x16x4f64(a1, b1, acc[1][1], 0, 0, 0);
    acc[1][2] = __builtin_amdgcn_mfma_f64_16x16x4f64(a1, b2, acc[1][2], 0, 0, 0);
    acc[1][3] = __builtin_amdgcn_mfma_f64_16x16x4f64(a1, b3, acc[1][3], 0, 0, 0);
  }
}

__global__ __launch_bounds__(256, 3) void conv_mfma_kernel(
    const float* __restrict__ fm, const float* __restrict__ W,
    const float* __restrict__ bias, double* __restrict__ x) {
  __shared__ float sbuf[2 * BUF_WORDS];
  const int ocb = blockIdx.x, rp = blockIdx.y, b = blockIdx.z;
  const int h0 = rp * 2;
  const int oc0 = ocb * 64;
  const int tid = threadIdx.x;
  const int wid = tid >> 6, l = tid & 63;
  const int q = l >> 4, r16 = l & 15;
  const int wm = wid >> 1, wn = wid & 1;

  const int wo = tid >> 2, wseg = tid & 3;
  const float* wbase = W + (size_t)(oc0 + wo) * 4608 + wseg * 9;
  const int wlds0 = (wseg * 9) * SW_STRIDE + wo;

  const float* fmb = fm + (size_t)b * CIN * NPIX;
  int ioff[5];
  int idls[5];
  bool sact[5], lact[5];
#pragma unroll
  for (int s = 0; s < 5; ++s) {
    int li = tid + 256 * s;
    sact[s] = li < 1056;
    int li_c = sact[s] ? li : 0;
    int c = li_c / 264, rem = li_c % 264, r = rem / 66, col = rem % 66;
    int gy = h0 - 1 + r, gx = col - 1;
    lact[s] = sact[s] && gy >= 0 && gy < FH && gx >= 0 && gx < FW;
    ioff[s] = lact[s] ? (c * NPIX + gy * FW + gx) : 0;
    idls[s] = SW_WORDS + c * SI_CSTRIDE + r * SI_RSTRIDE + col;
  }

  const int apos = q * SW_STRIDE + wm * 32 + r16;
  const int ipos = SW_WORDS + wn * SI_RSTRIDE + r16;
  int boff[9];
#pragma unroll
  for (int k0s = 0; k0s < 9; ++k0s) {
    int k = k0s * 4 + q;
    int c = k / 9, t = k - 9 * c;
    int dy = t / 3, dx = t - 3 * dy;
    boff[k0s] = c * SI_CSTRIDE + dy * SI_RSTRIDE + dx;
  }

  f64x4 acc[2][4];
#pragma unroll
  for (int tm = 0; tm < 2; ++tm)
#pragma unroll
    for (int tn = 0; tn < 4; ++tn)
#pragma unroll
      for (int v = 0; v < 4; ++v) acc[tm][tn][v] = 0.0;

  float wreg[9], ireg[5];

#define LOAD_REGS(t) do {                                            \
    const int cc_ = 4 * (t);                                         \
    _Pragma("unroll")                                                \
    for (int j = 0; j < 9; ++j) wreg[j] = wbase[cc_ * 9 + j];        \
    _Pragma("unroll")                                                \
    for (int s = 0; s < 5; ++s)                                      \
      ireg[s] = lact[s] ? fmb[(size_t)(ioff[s] + cc_ * NPIX)] : 0.f; \
  } while (0)

#define WRITE_LDS(base) do {                                         \
    _Pragma("unroll")                                                \
    for (int j = 0; j < 9; ++j) (base)[wlds0 + j * SW_STRIDE] = wreg[j]; \
    _Pragma("unroll")                                                \
    for (int s = 0; s < 5; ++s)                                      \
      if (sact[s]) (base)[idls[s]] = ireg[s];                        \
  } while (0)

  float* buf0 = sbuf;
  float* buf1 = sbuf + BUF_WORDS;

  LOAD_REGS(0);
  WRITE_LDS(buf0);
  __syncthreads();

  for (int tt = 0; tt < 64; ++tt) {
    const int t1 = 2 * tt + 1;
    LOAD_REGS(t1);
    __builtin_amdgcn_s_setprio(1);
    conv_compute(buf0 + apos, buf0 + ipos, boff, acc);
    __builtin_amdgcn_s_setprio(0);
    WRITE_LDS(buf1);
    __syncthreads();
    const int t2 = (t1 + 1 < 128) ? t1 + 1 : 127;
    LOAD_REGS(t2);
    __builtin_amdgcn_s_setprio(1);
    conv_compute(buf1 + apos, buf1 + ipos, boff, acc);
    __builtin_amdgcn_s_setprio(0);
    WRITE_LDS(buf0);
    __syncthreads();
  }

  int prow[4], pcol[4];
  {
    f64x4 probe = {0.0, 0.0, 0.0, 0.0};
    double pa = (q == 0) ? (double)r16 : ((q == 1) ? 1.0 : 0.0);
    double pb = (q == 0) ? 1.0 : ((q == 1) ? (double)(16 * r16) : 0.0);
    probe = __builtin_amdgcn_mfma_f64_16x16x4f64(pa, pb, probe, 0, 0, 0);
#pragma unroll
    for (int v = 0; v < 4; ++v) {
      int val = (int)(probe[v] + 0.5);
      prow[v] = val & 15;
      pcol[v] = (val >> 4) & 15;
    }
  }

#pragma unroll
  for (int tm = 0; tm < 2; ++tm) {
#pragma unroll
    for (int v = 0; v < 4; ++v) {
      const int oc = oc0 + wm * 32 + tm * 16 + prow[v];
      const double bv = (double)bias[oc];
      const int h = h0 + wn;
#pragma unroll
      for (int tn = 0; tn < 4; ++tn) {
        const int w = tn * 16 + pcol[v];
        double val = acc[tm][tn][v] + bv;
        val = val > 0.0 ? val : 0.0;
        x[(size_t)(b * COUT + oc) * NPIX + h * FW + w] = val;
      }
    }
  }
#undef LOAD_REGS
#undef WRITE_LDS
}

// =================== Winograd F(2x2,3x3) path (tile-chunked) =================
// U[pos][c][oc] = (G g G^T), G = [[1,0,0],[.5,.5,.5],[.5,-.5,.5],[0,0,1]]
__global__ __launch_bounds__(256) void wino_wt_kernel(
    const float* __restrict__ W, double* __restrict__ U) {
  const int id = blockIdx.x * 256 + threadIdx.x;   // 262144
  const int oc = id >> 9, c = id & 511;
  const float* g = W + (size_t)(oc * CIN + c) * 9;
  double g0[3], g1[3], g2[3];
#pragma unroll
  for (int j = 0; j < 3; ++j) {
    g0[j] = (double)g[j];
    g1[j] = (double)g[3 + j];
    g2[j] = (double)g[6 + j];
  }
  double T[4][3];
#pragma unroll
  for (int j = 0; j < 3; ++j) {
    T[0][j] = g0[j];
    T[1][j] = 0.5 * (g0[j] + g1[j] + g2[j]);
    T[2][j] = 0.5 * (g0[j] - g1[j] + g2[j]);
    T[3][j] = g2[j];
  }
  double* Ub = U + (size_t)c * 512 + oc;   // + pos*262144
#pragma unroll
  for (int xi = 0; xi < 4; ++xi) {
    double u0 = T[xi][0];
    double u1 = 0.5 * (T[xi][0] + T[xi][1] + T[xi][2]);
    double u2 = 0.5 * (T[xi][0] - T[xi][1] + T[xi][2]);
    double u3 = T[xi][2];
    Ub[(size_t)(xi * 4 + 0) * 262144] = u0;
    Ub[(size_t)(xi * 4 + 1) * 262144] = u1;
    Ub[(size_t)(xi * 4 + 2) * 262144] = u2;
    Ub[(size_t)(xi * 4 + 3) * 262144] = u3;
  }
}

// V[pos][c][rem] = B^T d B for chunk tiles [t0, t0+T) of image b.
// B^T = [[1,0,-1,0],[0,1,1,0],[0,-1,1,0],[0,1,0,-1]]
template <int T>
__global__ __launch_bounds__(256) void wino_in_kernel(
    const float* __restrict__ fm, double* __restrict__ V, int b, int t0) {
  const int id = blockIdx.x * 256 + threadIdx.x;   // 512*T
  const int c = id / T, rem = id % T;
  const int tyx = t0 + rem;
  const int ty = tyx >> 5, tx = tyx & 31;
  const float* src = fm + (size_t)(b * CIN + c) * NPIX;
  const int y0 = 2 * ty - 1, x0 = 2 * tx - 1;
  double d[4][4];
#pragma unroll
  for (int r = 0; r < 4; ++r) {
    int y = y0 + r;
#pragma unroll
    for (int s = 0; s < 4; ++s) {
      int xx = x0 + s;
      d[r][s] = (y >= 0 && y < FH && xx >= 0 && xx < FW)
                    ? (double)src[y * FW + xx] : 0.0;
    }
  }
  double Z[4][4];
#pragma unroll
  for (int s = 0; s < 4; ++s) {
    Z[0][s] = d[0][s] - d[2][s];
    Z[1][s] = d[1][s] + d[2][s];
    Z[2][s] = d[2][s] - d[1][s];
    Z[3][s] = d[1][s] - d[3][s];
  }
  double* Vb = V + (size_t)c * T + rem;   // + pos*512*T
#pragma unroll
  for (int xi = 0; xi < 4; ++xi) {
    double v0 = Z[xi][0] - Z[xi][2];
    double v1 = Z[xi][1] + Z[xi][2];
    double v2 = Z[xi][2] - Z[xi][1];
    double v3 = Z[xi][1] - Z[xi][3];
    Vb[(size_t)(xi * 4 + 0) * 512 * T] = v0;
    Vb[(size_t)(xi * 4 + 1) * 512 * T] = v1;
    Vb[(size_t)(xi * 4 + 2) * 512 * T] = v2;
    Vb[(size_t)(xi * 4 + 3) * 512 * T] = v3;
  }
}

// M[pos] = U[pos] (512oc x 512c) * V[pos] (512c x T tiles), f64 MFMA.
// Same feed pattern + probe-decoded D mapping as conv_mfma_kernel.
#define WSU_STRIDE 72
#define WSV_STRIDE 136
#define WSU_WORDS  (8 * WSU_STRIDE)              // 576
#define WBUF_WORDS (WSU_WORDS + 8 * WSV_STRIDE)  // 1664 f64 = 13312 B

__device__ __forceinline__ void wino_compute(
    const double* __restrict__ sA, const double* __restrict__ sB,
    f64x4 acc[2][4]) {
#pragma unroll
  for (int kg = 0; kg < 2; ++kg) {
    double a0 = sA[kg * 4 * WSU_STRIDE];
    double a1 = sA[kg * 4 * WSU_STRIDE + 16];
    const double* bp = sB + kg * 4 * WSV_STRIDE;
    double b0 = bp[0];
    double b1 = bp[16];
    double b2 = bp[32];
    double b3 = bp[48];
    acc[0][0] = __builtin_amdgcn_mfma_f64_16x16x4f64(a0, b0, acc[0][0], 0, 0, 0);
    acc[0][1] = __builtin_amdgcn_mfma_f64_16x16x4f64(a0, b1, acc[0][1], 0, 0, 0);
    acc[0][2] = __builtin_amdgcn_mfma_f64_16x16x4f64(a0, b2, acc[0][2], 0, 0, 0);
    acc[0][3] = __builtin_amdgcn_mfma_f64_16x16x4f64(a0, b3, acc[0][3], 0, 0, 0);
    acc[1][0] = __builtin_amdgcn_mfma_f64_16x16x4f64(a1, b0, acc[1][0], 0, 0, 0);
    acc[1][1] = __builtin_amdgcn_mfma_f64_16x16x4f64(a1, b1, acc[1][1], 0, 0, 0);
    acc[1][2] = __builtin_amdgcn_mfma_f64_16x16x4f64(a1, b2, acc[1][2], 0, 0, 0);
    acc[1][3] = __builtin_amdgcn_mfma_f64_16x16x4f64(a1, b3, acc[1][3], 0, 0, 0);
  }
}

template <int T>
__global__ __launch_bounds__(256, 3) void wino_gemm_kernel(
    const double* __restrict__ U, const double* __restrict__ V,
    double* __restrict__ M) {
  __shared__ double sbuf[2 * WBUF_WORDS];
  const int ocb = blockIdx.x, tb = blockIdx.y, pos = blockIdx.z;
  const int oc0 = ocb * 64, t0 = tb * 128;
  const int tid = threadIdx.x;
  const int wid = tid >> 6, l = tid & 63;
  const int q = l >> 4, r16 = l & 15;
  const int wm = wid >> 1, wn = wid & 1;   // 2(M) x 2(N) waves

  // staging maps (loop-invariant)
  const int ka = tid >> 5;                 // 0..7
  const int oc2 = (tid & 31) * 2;          // A: 2 f64/thread
  const int t4 = (tid & 31) * 4;           // B: 4 f64/thread
  const double* uSrc = U + (size_t)pos * 262144 + (size_t)ka * 512 + oc0 + oc2;
  const double* vSrc = V + (size_t)pos * 512 * T + (size_t)ka * T + t0 + t4;
  const int ua_lds = ka * WSU_STRIDE + oc2;
  const int vb_lds = WSU_WORDS + ka * WSV_STRIDE + t4;

  // fragment read bases
  const int apos = q * WSU_STRIDE + wm * 32 + r16;
  const int bpos = WSU_WORDS + q * WSV_STRIDE + wn * 64 + r16;

  f64x4 acc[2][4];
#pragma unroll
  for (int tm = 0; tm < 2; ++tm)
#pragma unroll
    for (int tn = 0; tn < 4; ++tn)
#pragma unroll
      for (int v = 0; v < 4; ++v) acc[tm][tn][v] = 0.0;

  f64x2 ra, rb0, rb1;

#define WLOAD(t) do {                                                  \
    const size_t cc_ = 8 * (size_t)(t);                                \
    ra  = *(const f64x2*)(uSrc + cc_ * 512);                           \
    rb0 = *(const f64x2*)(vSrc + cc_ * T);                             \
    rb1 = *(const f64x2*)(vSrc + cc_ * T + 2);                         \
  } while (0)

#define WSTORE(base) do {                                              \
    (base)[ua_lds] = ra[0]; (base)[ua_lds + 1] = ra[1];                \
    (base)[vb_lds] = rb0[0]; (base)[vb_lds + 1] = rb0[1];              \
    (base)[vb_lds + 2] = rb1[0]; (base)[vb_lds + 3] = rb1[1];          \
  } while (0)

  double* buf0 = sbuf;
  double* buf1 = sbuf + WBUF_WORDS;

  WLOAD(0);
  WSTORE(buf0);
  __syncthreads();

  for (int tt = 0; tt < 32; ++tt) {
    const int t1 = 2 * tt + 1;
    WLOAD(t1);
    __builtin_amdgcn_s_setprio(1);
    wino_compute(buf0 + apos, buf0 + bpos, acc);
    __builtin_amdgcn_s_setprio(0);
    WSTORE(buf1);
    __syncthreads();
    const int t2 = (t1 + 1 < 64) ? t1 + 1 : 63;
    WLOAD(t2);
    __builtin_amdgcn_s_setprio(1);
    wino_compute(buf1 + apos, buf1 + bpos, acc);
    __builtin_amdgcn_s_setprio(0);
    WSTORE(buf0);
    __syncthreads();
  }

  // probe-decoded D mapping (same as conv path)
  int prow[4], pcol[4];
  {
    f64x4 probe = {0.0, 0.0, 0.0, 0.0};
    double pa = (q == 0) ? (double)r16 : ((q == 1) ? 1.0 : 0.0);
    double pb = (q == 0) ? 1.0 : ((q == 1) ? (double)(16 * r16) : 0.0);
    probe = __builtin_amdgcn_mfma_f64_16x16x4f64(pa, pb, probe, 0, 0, 0);
#pragma unroll
    for (int v = 0; v < 4; ++v) {
      int val = (int)(probe[v] + 0.5);
      prow[v] = val & 15;
      pcol[v] = (val >> 4) & 15;
    }
  }

#pragma unroll
  for (int tm = 0; tm < 2; ++tm) {
#pragma unroll
    for (int v = 0; v < 4; ++v) {
      const int oc = oc0 + wm * 32 + tm * 16 + prow[v];
#pragma unroll
      for (int tn = 0; tn < 4; ++tn) {
        const int col = wn * 64 + tn * 16 + pcol[v];
        M[(size_t)pos * 512 * T + (size_t)oc * T + t0 + col] = acc[tm][tn][v];
      }
    }
  }
#undef WLOAD
#undef WSTORE
}

// x[b][oc][2ty+i][2tx+j] = relu( (A^T m A)[i][j] + bias ), A^T = [[1,1,1,0],[0,1,-1,-1]]
template <int T>
__global__ __launch_bounds__(256) void wino_out_kernel(
    const double* __restrict__ M, const float* __restrict__ bias,
    double* __restrict__ x, int b, int t0) {
  const int id = blockIdx.x * 256 + threadIdx.x;   // 512*T
  const int oc = id / T, rem = id % T;
  const int tyx = t0 + rem;
  const int ty = tyx >> 5, tx = tyx & 31;
  double m[4][4];
#pragma unroll
  for (int xi = 0; xi < 4; ++xi)
#pragma unroll
    for (int nu = 0; nu < 4; ++nu)
      m[xi][nu] = M[(size_t)(xi * 4 + nu) * 512 * T + (size_t)oc * T + rem];
  double P[2][4];
#pragma unroll
  for (int nu = 0; nu < 4; ++nu) {
    P[0][nu] = m[0][nu] + m[1][nu] + m[2][nu];
    P[1][nu] = m[1][nu] - m[2][nu] - m[3][nu];
  }
  const double bv = (double)bias[oc];
  double* xb = x + (size_t)(b * COUT + oc) * NPIX + (2 * ty) * FW + 2 * tx;
#pragma unroll
  for (int i = 0; i < 2; ++i) {
    double y0 = P[i][0] + P[i][1] + P[i][2] + bv;
    double y1 = P[i][1] - P[i][2] - P[i][3] + bv;
    y0 = y0 > 0.0 ? y0 : 0.0;
    y1 = y1 > 0.0 ? y1 : 0.0;
    xb[i * FW] = y0;
    xb[i * FW + 1] = y1;
  }
}

// ---------------- heads: 45 logits/pixel -> scores, boxes, sort keys ----------
__global__ __launch_bounds__(256) void heads_kernel(
    const double* __restrict__ x, const float* __restrict__ cls_w,
    const float* __restrict__ cls_b, const float* __restrict__ reg_w,
    const float* __restrict__ reg_b, const int* __restrict__ img_h,
    const int* __restrict__ img_w, double* __restrict__ scores,
    double* __restrict__ boxes, unsigned long long* __restrict__ keys) {
  __shared__ double sx[4096];
  __shared__ double swl[2880];
  const int b = blockIdx.x >> 6;
  const int ptile = blockIdx.x & 63;
  const int tx = threadIdx.x, ty = threadIdx.y;
  const int tid = ty * 64 + tx;

  double acc[12];
#pragma unroll
  for (int j = 0; j < 12; ++j) acc[j] = 0.0;

  for (int cc = 0; cc < CIN; cc += 64) {
    for (int li = tid; li < 4096; li += 256) {
      int ci = li >> 6, px = li & 63;
      sx[li] = x[((long)b * CIN + cc + ci) * NPIX + ptile * 64 + px];
    }
    for (int li = tid; li < 2880; li += 256) {
      int o = li >> 6, ci = li & 63;
      float wv = (o < 9) ? cls_w[o * CIN + cc + ci] : reg_w[(o - 9) * CIN + cc + ci];
      swl[li] = (double)wv;
    }
    __syncthreads();
#pragma unroll 4
    for (int ci = 0; ci < 64; ++ci) {
      double xv = sx[ci * 64 + tx];
#pragma unroll
      for (int j = 0; j < 12; ++j) {
        int o = ty + 4 * j;
        if (o < 45) acc[j] += swl[o * 64 + ci] * xv;
      }
    }
    __syncthreads();
  }

#pragma unroll
  for (int j = 0; j < 12; ++j) {
    int o = ty + 4 * j;
    if (o < 45) {
      double bv = (o < 9) ? (double)cls_b[o] : (double)reg_b[o - 9];
      swl[o * 64 + tx] = acc[j] + bv;
    }
  }
  __syncthreads();

  const double ih = (double)img_h[0], iw = (double)img_w[0];
  const double sth = ih / (double)FH, stw = iw / (double)FW;
  const double ratios[3] = {0.5, 1.0, 2.0};
  const double sizes[3] = {128.0, 256.0, 512.0};

  for (int it = tid; it < 576; it += 256) {
    int px = it / 9, a = it % 9;
    int p = ptile * 64 + px;
    int hh = p >> 6, ww = p & 63;
    double z = swl[a * 64 + px];
    double score = 1.0 / (1.0 + exp(-z));
    double d0 = swl[(9 + a * 4 + 0) * 64 + px];
    double d1 = swl[(9 + a * 4 + 1) * 64 + px];
    double d2 = swl[(9 + a * 4 + 2) * 64 + px];
    double d3 = swl[(9 + a * 4 + 3) * 64 + px];
    double ratio = ratios[a / 3], size = sizes[a % 3];
    double hr = sqrt(ratio), wr = 1.0 / hr;
    double wsz = wr * size, hsz = hr * size;
    double sxc = (double)ww * stw, syc = (double)hh * sth;
    double ax0 = sxc - wsz * 0.5, ax1 = sxc + wsz * 0.5;
    double ay0 = syc - hsz * 0.5, ay1 = syc + hsz * 0.5;
    double aw = ax1 - ax0, ah = ay1 - ay0;
    double acx = ax0 + 0.5 * aw, acy = ay0 + 0.5 * ah;
    double pcx = d0 * aw + acx, pcy = d1 * ah + acy;
    double pw = exp(d2) * aw, ph = exp(d3) * ah;
    double bx0 = pcx - 0.5 * pw, by0 = pcy - 0.5 * ph;
    double bx1 = pcx + 0.5 * pw, by1 = pcy + 0.5 * ph;
    bx0 = fmin(fmax(bx0, 0.0), iw); bx1 = fmin(fmax(bx1, 0.0), iw);
    by0 = fmin(fmax(by0, 0.0), ih); by1 = fmin(fmax(by1, 0.0), ih);
    long n = (long)p * 9 + a;
    long base = (long)b * NANCH + n;
    boxes[base * 4 + 0] = bx0; boxes[base * 4 + 1] = by0;
    boxes[base * 4 + 2] = bx1; boxes[base * 4 + 3] = by1;
    scores[base] = score;
    unsigned long long bits = (unsigned long long)__double_as_longlong(score);
    keys[(long)b * NPAD + n] =
        ~((bits & 0xFFFFFFFFFFFF0000ull) | (0xFFFFull - (unsigned long long)n));
  }
}

// ---------------- bitonic sort of 4096 u64 in LDS (ascending) ----------------
__device__ inline void bitonic4096(unsigned long long* s, int tid) {
  for (int k = 2; k <= 4096; k <<= 1) {
    for (int j = k >> 1; j > 0; j >>= 1) {
#pragma unroll 2
      for (int t = tid; t < 2048; t += 1024) {
        int i = ((t & ~(j - 1)) << 1) | (t & (j - 1));
        int p = i | j;
        bool up = ((i & k) == 0);
        unsigned long long a = s[i], c = s[p];
        if ((a > c) == up) { s[i] = c; s[p] = a; }
      }
      __syncthreads();
    }
  }
}

__global__ __launch_bounds__(1024) void sort_topk_kernel(
    const unsigned long long* __restrict__ in, unsigned long long* __restrict__ out,
    long in_stride, long out_stride) {
  __shared__ unsigned long long s[4096];
  const int b = blockIdx.y, q = blockIdx.x, tid = threadIdx.x;
  const unsigned long long* ip = in + (long)b * in_stride + (long)q * 4096;
#pragma unroll 4
  for (int l = tid; l < 4096; l += 1024) s[l] = ip[l];
  __syncthreads();
  bitonic4096(s, tid);
  unsigned long long* op = out + (long)b * out_stride + (long)q * 1024;
  op[tid] = s[tid];
}

__global__ __launch_bounds__(1024) void sort_final_kernel(
    const unsigned long long* __restrict__ in, int* __restrict__ sel) {
  __shared__ unsigned long long s[4096];
  const int b = blockIdx.x, tid = threadIdx.x;
  const unsigned long long* ip = in + (long)b * 4096;
#pragma unroll 4
  for (int l = tid; l < 4096; l += 1024) s[l] = ip[l];
  __syncthreads();
  bitonic4096(s, tid);
  if (tid < KPRE) sel[b * 1024 + tid] = (int)(s[tid] & 0xFFFFull);
}

// ---------------- greedy sequential NMS, f64, one block per image ------------
__global__ __launch_bounds__(256) void nms_kernel(
    const double* __restrict__ boxes, const int* __restrict__ sel,
    int* __restrict__ keep) {
  __shared__ double X0[KPRE], Y0[KPRE], X1[KPRE], Y1[KPRE], AR[KPRE];
  __shared__ int KP[KPRE];
  const int b = blockIdx.x, tid = threadIdx.x;
  for (int r = tid; r < KPRE; r += 256) {
    int n = sel[b * 1024 + r];
    const double* bp = boxes + ((long)b * NANCH + n) * 4;
    double x0 = bp[0], y0 = bp[1], x1 = bp[2], y1 = bp[3];
    X0[r] = x0; Y0[r] = y0; X1[r] = x1; Y1[r] = y1;
    AR[r] = (x1 - x0) * (y1 - y0);
    KP[r] = 1;
  }
  __syncthreads();
  for (int i = 0; i < KPRE - 1; ++i) {
    if (KP[i]) {
      double xi0 = X0[i], yi0 = Y0[i], xi1 = X1[i], yi1 = Y1[i], ai = AR[i];
      for (int j = i + 1 + tid; j < KPRE; j += 256) {
        double lx = fmax(xi0, X0[j]), ly = fmax(yi0, Y0[j]);
        double rx = fmin(xi1, X1[j]), ry = fmin(yi1, Y1[j]);
        double w = rx - lx; w = fmax(w, 0.0);
        double h = ry - ly; h = fmax(h, 0.0);
        double inter = w * h;
        double iou = inter / (ai + AR[j] - inter + 1e-9);
        if (iou > 0.7) KP[j] = 0;
      }
    }
    __syncthreads();
  }
  for (int r = tid; r < KPRE; r += 256) keep[b * 1024 + r] = KP[r];
}

// ---------------- output: kept-first stable order, zero pad ------------------
__global__ __launch_bounds__(1024) void out_kernel(
    const double* __restrict__ boxes, const double* __restrict__ scores,
    const int* __restrict__ sel, const int* __restrict__ keep,
    float* __restrict__ out) {
  const int b = blockIdx.x, tid = threadIdx.x;
  int kv = (tid < KPRE) ? keep[b * 1024 + tid] : 0;
  unsigned long long m = __ballot(kv != 0);
  int lane = tid & 63, wid = tid >> 6;
  __shared__ int wcnt[16], woff[16], tot;
  if (lane == 0) wcnt[wid] = __popcll(m);
  __syncthreads();
  if (tid == 0) {
    int s = 0;
    for (int w2 = 0; w2 < 16; ++w2) { woff[w2] = s; s += wcnt[w2]; }
    tot = s;
  }
  __syncthreads();
  int before = __popcll(m & ((1ull << lane) - 1ull));
  int pref = woff[wid] + before;
  if (tid < KPRE) {
    int pos = kv ? pref : (tot + (tid - pref));
    if (pos < KPOST) {
      float* o = out + ((long)b * KPOST + pos) * 5;
      if (kv) {
        int n = sel[b * 1024 + tid];
        const double* bp = boxes + ((long)b * NANCH + n) * 4;
        o[0] = (float)bp[0]; o[1] = (float)bp[1];
        o[2] = (float)bp[2]; o[3] = (float)bp[3];
        o[4] = (float)scores[(long)b * NANCH + n];
      } else {
        o[0] = 0.f; o[1] = 0.f; o[2] = 0.f; o[3] = 0.f; o[4] = 0.f;
      }
    }
  }
}

extern "C" void kernel_launch(void* const* d_in, const int* in_sizes, int n_in,
                              void* d_out, int out_size, void* d_ws, size_t ws_size,
                              hipStream_t stream) {
  const float* fm     = (const float*)d_in[0];
  const float* base_w = (const float*)d_in[1];
  const float* base_b = (const float*)d_in[2];
  const float* cls_w  = (const float*)d_in[3];
  const float* cls_b  = (const float*)d_in[4];
  const float* reg_w  = (const float*)d_in[5];
  const float* reg_b  = (const float*)d_in[6];
  const int* img_h    = (const int*)d_in[7];
  const int* img_w    = (const int*)d_in[8];
  float* out          = (float*)d_out;

  if (ws_size < WS_NEEDED) return;  // visible failure rather than corruption

  char* ws = (char*)d_ws;
  double* x                 = (double*)(ws + OFF_X);
  double* scores            = (double*)(ws + OFF_SCORES);
  double* boxes             = (double*)(ws + OFF_BOXES);
  unsigned long long* keys  = (unsigned long long*)(ws + OFF_KEYS);
  unsigned long long* buf1  = (unsigned long long*)(ws + OFF_BUF1);
  unsigned long long* buf2  = (unsigned long long*)(ws + OFF_BUF2);
  int* sel                  = (int*)(ws + OFF_SEL);
  int* keep                 = (int*)(ws + OFF_KEEP);

  // pad keys (anchors 36864..65535) and buf1 (chunks 9..15) with worst key
  hipMemsetAsync(ws + OFF_KEYS, 0xFF, 4194304ull + 1048576ull, stream);

  if (ws_size >= WS_WINO_FULL) {
    // Winograd, full image per launch-set (T=1024)
    double* U = (double*)(ws + WOFF_U);
    double* V = (double*)(ws + WOFF_V);
    double* M = (double*)(ws + WOFF_V + 67108864ull);
    wino_wt_kernel<<<dim3(1024), dim3(256), 0, stream>>>(base_w, U);
    for (int b = 0; b < BS; ++b) {
      wino_in_kernel<1024><<<dim3(2048), dim3(256), 0, stream>>>(fm, V, b, 0);
      wino_gemm_kernel<1024><<<dim3(8, 8, 16), dim3(256), 0, stream>>>(U, V, M);
      wino_out_kernel<1024><<<dim3(2048), dim3(256), 0, stream>>>(M, base_b, x, b, 0);
    }
  } else if (ws_size >= WS_WINO_HALF) {
    // Winograd, half-image chunks (T=512)
    double* U = (double*)(ws + WOFF_U);
    double* V = (double*)(ws + WOFF_V);
    double* M = (double*)(ws + WOFF_V + 33554432ull);
    wino_wt_kernel<<<dim3(1024), dim3(256), 0, stream>>>(base_w, U);
    for (int b = 0; b < BS; ++b) {
      for (int t0 = 0; t0 < 1024; t0 += 512) {
        wino_in_kernel<512><<<dim3(1024), dim3(256), 0, stream>>>(fm, V, b, t0);
        wino_gemm_kernel<512><<<dim3(8, 4, 16), dim3(256), 0, stream>>>(U, V, M);
        wino_out_kernel<512><<<dim3(1024), dim3(256), 0, stream>>>(M, base_b, x, b, t0);
      }
    }
  } else {
    // direct implicit-GEMM conv (R6 path)
    conv_mfma_kernel<<<dim3(8, 32, 8), dim3(256), 0, stream>>>(fm, base_w, base_b, x);
  }

  heads_kernel<<<dim3(512), dim3(64, 4), 0, stream>>>(
      x, cls_w, cls_b, reg_w, reg_b, img_h, img_w, scores, boxes, keys);
  sort_topk_kernel<<<dim3(9, 8), dim3(1024), 0, stream>>>(keys, buf1, 65536, 16384);
  sort_topk_kernel<<<dim3(4, 8), dim3(1024), 0, stream>>>(buf1, buf2, 16384, 4096);
  sort_final_kernel<<<dim3(8), dim3(1024), 0, stream>>>(buf2, sel);
  nms_kernel<<<dim3(8), dim3(256), 0, stream>>>(boxes, sel, keep);
  out_kernel<<<dim3(8), dim3(1024), 0, stream>>>(boxes, scores, sel, keep, out);
}

// Round 9
// 1985.627 us; speedup vs baseline: 1.5428x; 1.1443x over previous
//
#include <hip/hip_runtime.h>
#include <math.h>

// RPNHead: conv3x3(512->512)+ReLU -> cls(9)/reg(36) 1x1 -> sigmoid/box-decode
// -> per-image exact top-1000 (by f64 score, index tie-break) -> greedy NMS
// -> [8,300,5] f32 output (kept-first stable order, zero-padded).
//
// Score/box pipeline in fp64 so top-k ordering and NMS decisions match a
// float64 numpy reference exactly (adjacent-score spacing ~5e-5..5e-8 >> f64
// noise ~1e-16; f32 would swap ranks -> wrong rows -> absmax ~1000).
//
// R2-R4: conv as implicit-GEMM on v_mfma_f64_16x16x4_f64; probe-decoded C/D
//        layout (gfx950 f64 MFMA mapping differs from CDNA2 docs).
// R5: f32 LDS, stride-80 pad, dbuf+T14, hoisted addressing. 2647us, 81%.
// R6: occupancy 2->3+ waves/SIMD + setprio. conv 2530us, MfmaUtil 85.5%.
// R7: Winograd full-image tier never ran => ws < 319.4MB.
// R8: tile-chunked Winograd T=512 (252.2MB) RAN: total 2272us. ws bracketed
//     [252.2, 319.4). New top dispatch: nms_kernel 418us (8 blocks, 1000
//     serial barrier iterations -- 99% overhead, work content ~5us).
// R9: NMS overhaul: parallel bitmask matrix (all CUs, LDS-staged boxes,
//     bank-conflict-free via +w rotation) + single-wave LDS scan per image
//     (no barriers). Same f64 IoU + eps -> bit-identical decisions.
//     Mask (1MB) reuses the x region (dead after heads_kernel).

typedef double f64x4 __attribute__((ext_vector_type(4)));
typedef double f64x2 __attribute__((ext_vector_type(2)));

#define BS 8
#define CIN 512
#define COUT 512
#define FH 64
#define FW 64
#define NA 9
#define NPIX (FH*FW)          // 4096
#define NANCH (NPIX*NA)       // 36864
#define NPAD 65536
#define KPRE 1000
#define KPOST 300

// ---- workspace layout (bytes) ----
#define OFF_X      0ull                                   // 8*512*4096 f64 = 134217728
#define OFF_SCORES (OFF_X + 134217728ull)                 // 8*36864 f64    = 2359296
#define OFF_BOXES  (OFF_SCORES + 2359296ull)              // 8*36864*4 f64  = 9437184
#define OFF_KEYS   (OFF_BOXES + 9437184ull)               // 8*65536 u64    = 4194304
#define OFF_BUF1   (OFF_KEYS + 4194304ull)                // 8*16*1024 u64  = 1048576
#define OFF_BUF2   (OFF_BUF1 + 1048576ull)                // 8*4*1024 u64   = 262144
#define OFF_SEL    (OFF_BUF2 + 262144ull)                 // 8*1024 i32     = 32768
#define OFF_KEEP   (OFF_SEL + 32768ull)                   // 8*1024 i32     = 32768
#define WS_NEEDED  (OFF_KEEP + 32768ull)                  // 151584768
// NMS suppression-mask matrix: reuses OFF_X (x dead after heads_kernel).
#define OFF_MASK   OFF_X                                  // 8*1024*16 u64  = 1048576
// Winograd extension
#define WOFF_U        WS_NEEDED                           // 16*512*512 f64 = 33554432
#define WOFF_V        (WOFF_U + 33554432ull)
#define WS_WINO_FULL  (WOFF_V + 67108864ull + 67108864ull)  // 319356928
#define WS_WINO_HALF  (WOFF_V + 33554432ull + 33554432ull)  // 252248064

// =================== R6 direct-conv path (fallback) ==========================
#define SW_STRIDE 80
#define SW_WORDS  (36 * SW_STRIDE)
#define SI_RSTRIDE 80
#define SI_CSTRIDE 320
#define BUF_WORDS (SW_WORDS + 4 * SI_CSTRIDE)

__device__ __forceinline__ void conv_compute(
    const float* __restrict__ sWp, const float* __restrict__ sIp,
    const int* __restrict__ boff, f64x4 acc[2][4]) {
#pragma unroll
  for (int k0s = 0; k0s < 9; ++k0s) {
    double a0 = (double)sWp[k0s * 4 * SW_STRIDE];
    double a1 = (double)sWp[k0s * 4 * SW_STRIDE + 16];
    const float* bp = sIp + boff[k0s];
    double b0 = (double)bp[0];
    double b1 = (double)bp[16];
    double b2 = (double)bp[32];
    double b3 = (double)bp[48];
    acc[0][0] = __builtin_amdgcn_mfma_f64_16x16x4f64(a0, b0, acc[0][0], 0, 0, 0);
    acc[0][1] = __builtin_amdgcn_mfma_f64_16x16x4f64(a0, b1, acc[0][1], 0, 0, 0);
    acc[0][2] = __builtin_amdgcn_mfma_f64_16x16x4f64(a0, b2, acc[0][2], 0, 0, 0);
    acc[0][3] = __builtin_amdgcn_mfma_f64_16x16x4f64(a0, b3, acc[0][3], 0, 0, 0);
    acc[1][0] = __builtin_amdgcn_mfma_f64_16x16x4f64(a1, b0, acc[1][0], 0, 0, 0);
    acc[1][1] = __builtin_amdgcn_mfma_f64_16x16x4f64(a1, b1, acc[1][1], 0, 0, 0);
    acc[1][2] = __builtin_amdgcn_mfma_f64_16x16x4f64(a1, b2, acc[1][2], 0, 0, 0);
    acc[1][3] = __builtin_amdgcn_mfma_f64_16x16x4f64(a1, b3, acc[1][3], 0, 0, 0);
  }
}

__global__ __launch_bounds__(256, 3) void conv_mfma_kernel(
    const float* __restrict__ fm, const float* __restrict__ W,
    const float* __restrict__ bias, double* __restrict__ x) {
  __shared__ float sbuf[2 * BUF_WORDS];
  const int ocb = blockIdx.x, rp = blockIdx.y, b = blockIdx.z;
  const int h0 = rp * 2;
  const int oc0 = ocb * 64;
  const int tid = threadIdx.x;
  const int wid = tid >> 6, l = tid & 63;
  const int q = l >> 4, r16 = l & 15;
  const int wm = wid >> 1, wn = wid & 1;

  const int wo = tid >> 2, wseg = tid & 3;
  const float* wbase = W + (size_t)(oc0 + wo) * 4608 + wseg * 9;
  const int wlds0 = (wseg * 9) * SW_STRIDE + wo;

  const float* fmb = fm + (size_t)b * CIN * NPIX;
  int ioff[5];
  int idls[5];
  bool sact[5], lact[5];
#pragma unroll
  for (int s = 0; s < 5; ++s) {
    int li = tid + 256 * s;
    sact[s] = li < 1056;
    int li_c = sact[s] ? li : 0;
    int c = li_c / 264, rem = li_c % 264, r = rem / 66, col = rem % 66;
    int gy = h0 - 1 + r, gx = col - 1;
    lact[s] = sact[s] && gy >= 0 && gy < FH && gx >= 0 && gx < FW;
    ioff[s] = lact[s] ? (c * NPIX + gy * FW + gx) : 0;
    idls[s] = SW_WORDS + c * SI_CSTRIDE + r * SI_RSTRIDE + col;
  }

  const int apos = q * SW_STRIDE + wm * 32 + r16;
  const int ipos = SW_WORDS + wn * SI_RSTRIDE + r16;
  int boff[9];
#pragma unroll
  for (int k0s = 0; k0s < 9; ++k0s) {
    int k = k0s * 4 + q;
    int c = k / 9, t = k - 9 * c;
    int dy = t / 3, dx = t - 3 * dy;
    boff[k0s] = c * SI_CSTRIDE + dy * SI_RSTRIDE + dx;
  }

  f64x4 acc[2][4];
#pragma unroll
  for (int tm = 0; tm < 2; ++tm)
#pragma unroll
    for (int tn = 0; tn < 4; ++tn)
#pragma unroll
      for (int v = 0; v < 4; ++v) acc[tm][tn][v] = 0.0;

  float wreg[9], ireg[5];

#define LOAD_REGS(t) do {                                            \
    const int cc_ = 4 * (t);                                         \
    _Pragma("unroll")                                                \
    for (int j = 0; j < 9; ++j) wreg[j] = wbase[cc_ * 9 + j];        \
    _Pragma("unroll")                                                \
    for (int s = 0; s < 5; ++s)                                      \
      ireg[s] = lact[s] ? fmb[(size_t)(ioff[s] + cc_ * NPIX)] : 0.f; \
  } while (0)

#define WRITE_LDS(base) do {                                         \
    _Pragma("unroll")                                                \
    for (int j = 0; j < 9; ++j) (base)[wlds0 + j * SW_STRIDE] = wreg[j]; \
    _Pragma("unroll")                                                \
    for (int s = 0; s < 5; ++s)                                      \
      if (sact[s]) (base)[idls[s]] = ireg[s];                        \
  } while (0)

  float* buf0 = sbuf;
  float* buf1 = sbuf + BUF_WORDS;

  LOAD_REGS(0);
  WRITE_LDS(buf0);
  __syncthreads();

  for (int tt = 0; tt < 64; ++tt) {
    const int t1 = 2 * tt + 1;
    LOAD_REGS(t1);
    __builtin_amdgcn_s_setprio(1);
    conv_compute(buf0 + apos, buf0 + ipos, boff, acc);
    __builtin_amdgcn_s_setprio(0);
    WRITE_LDS(buf1);
    __syncthreads();
    const int t2 = (t1 + 1 < 128) ? t1 + 1 : 127;
    LOAD_REGS(t2);
    __builtin_amdgcn_s_setprio(1);
    conv_compute(buf1 + apos, buf1 + ipos, boff, acc);
    __builtin_amdgcn_s_setprio(0);
    WRITE_LDS(buf0);
    __syncthreads();
  }

  int prow[4], pcol[4];
  {
    f64x4 probe = {0.0, 0.0, 0.0, 0.0};
    double pa = (q == 0) ? (double)r16 : ((q == 1) ? 1.0 : 0.0);
    double pb = (q == 0) ? 1.0 : ((q == 1) ? (double)(16 * r16) : 0.0);
    probe = __builtin_amdgcn_mfma_f64_16x16x4f64(pa, pb, probe, 0, 0, 0);
#pragma unroll
    for (int v = 0; v < 4; ++v) {
      int val = (int)(probe[v] + 0.5);
      prow[v] = val & 15;
      pcol[v] = (val >> 4) & 15;
    }
  }

#pragma unroll
  for (int tm = 0; tm < 2; ++tm) {
#pragma unroll
    for (int v = 0; v < 4; ++v) {
      const int oc = oc0 + wm * 32 + tm * 16 + prow[v];
      const double bv = (double)bias[oc];
      const int h = h0 + wn;
#pragma unroll
      for (int tn = 0; tn < 4; ++tn) {
        const int w = tn * 16 + pcol[v];
        double val = acc[tm][tn][v] + bv;
        val = val > 0.0 ? val : 0.0;
        x[(size_t)(b * COUT + oc) * NPIX + h * FW + w] = val;
      }
    }
  }
#undef LOAD_REGS
#undef WRITE_LDS
}

// =================== Winograd F(2x2,3x3) path (tile-chunked) =================
__global__ __launch_bounds__(256) void wino_wt_kernel(
    const float* __restrict__ W, double* __restrict__ U) {
  const int id = blockIdx.x * 256 + threadIdx.x;   // 262144
  const int oc = id >> 9, c = id & 511;
  const float* g = W + (size_t)(oc * CIN + c) * 9;
  double g0[3], g1[3], g2[3];
#pragma unroll
  for (int j = 0; j < 3; ++j) {
    g0[j] = (double)g[j];
    g1[j] = (double)g[3 + j];
    g2[j] = (double)g[6 + j];
  }
  double T[4][3];
#pragma unroll
  for (int j = 0; j < 3; ++j) {
    T[0][j] = g0[j];
    T[1][j] = 0.5 * (g0[j] + g1[j] + g2[j]);
    T[2][j] = 0.5 * (g0[j] - g1[j] + g2[j]);
    T[3][j] = g2[j];
  }
  double* Ub = U + (size_t)c * 512 + oc;   // + pos*262144
#pragma unroll
  for (int xi = 0; xi < 4; ++xi) {
    double u0 = T[xi][0];
    double u1 = 0.5 * (T[xi][0] + T[xi][1] + T[xi][2]);
    double u2 = 0.5 * (T[xi][0] - T[xi][1] + T[xi][2]);
    double u3 = T[xi][2];
    Ub[(size_t)(xi * 4 + 0) * 262144] = u0;
    Ub[(size_t)(xi * 4 + 1) * 262144] = u1;
    Ub[(size_t)(xi * 4 + 2) * 262144] = u2;
    Ub[(size_t)(xi * 4 + 3) * 262144] = u3;
  }
}

template <int T>
__global__ __launch_bounds__(256) void wino_in_kernel(
    const float* __restrict__ fm, double* __restrict__ V, int b, int t0) {
  const int id = blockIdx.x * 256 + threadIdx.x;   // 512*T
  const int c = id / T, rem = id % T;
  const int tyx = t0 + rem;
  const int ty = tyx >> 5, tx = tyx & 31;
  const float* src = fm + (size_t)(b * CIN + c) * NPIX;
  const int y0 = 2 * ty - 1, x0 = 2 * tx - 1;
  double d[4][4];
#pragma unroll
  for (int r = 0; r < 4; ++r) {
    int y = y0 + r;
#pragma unroll
    for (int s = 0; s < 4; ++s) {
      int xx = x0 + s;
      d[r][s] = (y >= 0 && y < FH && xx >= 0 && xx < FW)
                    ? (double)src[y * FW + xx] : 0.0;
    }
  }
  double Z[4][4];
#pragma unroll
  for (int s = 0; s < 4; ++s) {
    Z[0][s] = d[0][s] - d[2][s];
    Z[1][s] = d[1][s] + d[2][s];
    Z[2][s] = d[2][s] - d[1][s];
    Z[3][s] = d[1][s] - d[3][s];
  }
  double* Vb = V + (size_t)c * T + rem;   // + pos*512*T
#pragma unroll
  for (int xi = 0; xi < 4; ++xi) {
    double v0 = Z[xi][0] - Z[xi][2];
    double v1 = Z[xi][1] + Z[xi][2];
    double v2 = Z[xi][2] - Z[xi][1];
    double v3 = Z[xi][1] - Z[xi][3];
    Vb[(size_t)(xi * 4 + 0) * 512 * T] = v0;
    Vb[(size_t)(xi * 4 + 1) * 512 * T] = v1;
    Vb[(size_t)(xi * 4 + 2) * 512 * T] = v2;
    Vb[(size_t)(xi * 4 + 3) * 512 * T] = v3;
  }
}

#define WSU_STRIDE 72
#define WSV_STRIDE 136
#define WSU_WORDS  (8 * WSU_STRIDE)              // 576
#define WBUF_WORDS (WSU_WORDS + 8 * WSV_STRIDE)  // 1664 f64 = 13312 B

__device__ __forceinline__ void wino_compute(
    const double* __restrict__ sA, const double* __restrict__ sB,
    f64x4 acc[2][4]) {
#pragma unroll
  for (int kg = 0; kg < 2; ++kg) {
    double a0 = sA[kg * 4 * WSU_STRIDE];
    double a1 = sA[kg * 4 * WSU_STRIDE + 16];
    const double* bp = sB + kg * 4 * WSV_STRIDE;
    double b0 = bp[0];
    double b1 = bp[16];
    double b2 = bp[32];
    double b3 = bp[48];
    acc[0][0] = __builtin_amdgcn_mfma_f64_16x16x4f64(a0, b0, acc[0][0], 0, 0, 0);
    acc[0][1] = __builtin_amdgcn_mfma_f64_16x16x4f64(a0, b1, acc[0][1], 0, 0, 0);
    acc[0][2] = __builtin_amdgcn_mfma_f64_16x16x4f64(a0, b2, acc[0][2], 0, 0, 0);
    acc[0][3] = __builtin_amdgcn_mfma_f64_16x16x4f64(a0, b3, acc[0][3], 0, 0, 0);
    acc[1][0] = __builtin_amdgcn_mfma_f64_16x16x4f64(a1, b0, acc[1][0], 0, 0, 0);
    acc[1][1] = __builtin_amdgcn_mfma_f64_16x16x4f64(a1, b1, acc[1][1], 0, 0, 0);
    acc[1][2] = __builtin_amdgcn_mfma_f64_16x16x4f64(a1, b2, acc[1][2], 0, 0, 0);
    acc[1][3] = __builtin_amdgcn_mfma_f64_16x16x4f64(a1, b3, acc[1][3], 0, 0, 0);
  }
}

template <int T>
__global__ __launch_bounds__(256, 3) void wino_gemm_kernel(
    const double* __restrict__ U, const double* __restrict__ V,
    double* __restrict__ M) {
  __shared__ double sbuf[2 * WBUF_WORDS];
  const int ocb = blockIdx.x, tb = blockIdx.y, pos = blockIdx.z;
  const int oc0 = ocb * 64, t0 = tb * 128;
  const int tid = threadIdx.x;
  const int wid = tid >> 6, l = tid & 63;
  const int q = l >> 4, r16 = l & 15;
  const int wm = wid >> 1, wn = wid & 1;   // 2(M) x 2(N) waves

  const int ka = tid >> 5;                 // 0..7
  const int oc2 = (tid & 31) * 2;          // A: 2 f64/thread
  const int t4 = (tid & 31) * 4;           // B: 4 f64/thread
  const double* uSrc = U + (size_t)pos * 262144 + (size_t)ka * 512 + oc0 + oc2;
  const double* vSrc = V + (size_t)pos * 512 * T + (size_t)ka * T + t0 + t4;
  const int ua_lds = ka * WSU_STRIDE + oc2;
  const int vb_lds = WSU_WORDS + ka * WSV_STRIDE + t4;

  const int apos = q * WSU_STRIDE + wm * 32 + r16;
  const int bpos = WSU_WORDS + q * WSV_STRIDE + wn * 64 + r16;

  f64x4 acc[2][4];
#pragma unroll
  for (int tm = 0; tm < 2; ++tm)
#pragma unroll
    for (int tn = 0; tn < 4; ++tn)
#pragma unroll
      for (int v = 0; v < 4; ++v) acc[tm][tn][v] = 0.0;

  f64x2 ra, rb0, rb1;

#define WLOAD(t) do {                                                  \
    const size_t cc_ = 8 * (size_t)(t);                                \
    ra  = *(const f64x2*)(uSrc + cc_ * 512);                           \
    rb0 = *(const f64x2*)(vSrc + cc_ * T);                             \
    rb1 = *(const f64x2*)(vSrc + cc_ * T + 2);                         \
  } while (0)

#define WSTORE(base) do {                                              \
    (base)[ua_lds] = ra[0]; (base)[ua_lds + 1] = ra[1];                \
    (base)[vb_lds] = rb0[0]; (base)[vb_lds + 1] = rb0[1];              \
    (base)[vb_lds + 2] = rb1[0]; (base)[vb_lds + 3] = rb1[1];          \
  } while (0)

  double* buf0 = sbuf;
  double* buf1 = sbuf + WBUF_WORDS;

  WLOAD(0);
  WSTORE(buf0);
  __syncthreads();

  for (int tt = 0; tt < 32; ++tt) {
    const int t1 = 2 * tt + 1;
    WLOAD(t1);
    __builtin_amdgcn_s_setprio(1);
    wino_compute(buf0 + apos, buf0 + bpos, acc);
    __builtin_amdgcn_s_setprio(0);
    WSTORE(buf1);
    __syncthreads();
    const int t2 = (t1 + 1 < 64) ? t1 + 1 : 63;
    WLOAD(t2);
    __builtin_amdgcn_s_setprio(1);
    wino_compute(buf1 + apos, buf1 + bpos, acc);
    __builtin_amdgcn_s_setprio(0);
    WSTORE(buf0);
    __syncthreads();
  }

  int prow[4], pcol[4];
  {
    f64x4 probe = {0.0, 0.0, 0.0, 0.0};
    double pa = (q == 0) ? (double)r16 : ((q == 1) ? 1.0 : 0.0);
    double pb = (q == 0) ? 1.0 : ((q == 1) ? (double)(16 * r16) : 0.0);
    probe = __builtin_amdgcn_mfma_f64_16x16x4f64(pa, pb, probe, 0, 0, 0);
#pragma unroll
    for (int v = 0; v < 4; ++v) {
      int val = (int)(probe[v] + 0.5);
      prow[v] = val & 15;
      pcol[v] = (val >> 4) & 15;
    }
  }

#pragma unroll
  for (int tm = 0; tm < 2; ++tm) {
#pragma unroll
    for (int v = 0; v < 4; ++v) {
      const int oc = oc0 + wm * 32 + tm * 16 + prow[v];
#pragma unroll
      for (int tn = 0; tn < 4; ++tn) {
        const int col = wn * 64 + tn * 16 + pcol[v];
        M[(size_t)pos * 512 * T + (size_t)oc * T + t0 + col] = acc[tm][tn][v];
      }
    }
  }
#undef WLOAD
#undef WSTORE
}

template <int T>
__global__ __launch_bounds__(256) void wino_out_kernel(
    const double* __restrict__ M, const float* __restrict__ bias,
    double* __restrict__ x, int b, int t0) {
  const int id = blockIdx.x * 256 + threadIdx.x;   // 512*T
  const int oc = id / T, rem = id % T;
  const int tyx = t0 + rem;
  const int ty = tyx >> 5, tx = tyx & 31;
  double m[4][4];
#pragma unroll
  for (int xi = 0; xi < 4; ++xi)
#pragma unroll
    for (int nu = 0; nu < 4; ++nu)
      m[xi][nu] = M[(size_t)(xi * 4 + nu) * 512 * T + (size_t)oc * T + rem];
  double P[2][4];
#pragma unroll
  for (int nu = 0; nu < 4; ++nu) {
    P[0][nu] = m[0][nu] + m[1][nu] + m[2][nu];
    P[1][nu] = m[1][nu] - m[2][nu] - m[3][nu];
  }
  const double bv = (double)bias[oc];
  double* xb = x + (size_t)(b * COUT + oc) * NPIX + (2 * ty) * FW + 2 * tx;
#pragma unroll
  for (int i = 0; i < 2; ++i) {
    double y0 = P[i][0] + P[i][1] + P[i][2] + bv;
    double y1 = P[i][1] - P[i][2] - P[i][3] + bv;
    y0 = y0 > 0.0 ? y0 : 0.0;
    y1 = y1 > 0.0 ? y1 : 0.0;
    xb[i * FW] = y0;
    xb[i * FW + 1] = y1;
  }
}

// ---------------- heads: 45 logits/pixel -> scores, boxes, sort keys ----------
__global__ __launch_bounds__(256) void heads_kernel(
    const double* __restrict__ x, const float* __restrict__ cls_w,
    const float* __restrict__ cls_b, const float* __restrict__ reg_w,
    const float* __restrict__ reg_b, const int* __restrict__ img_h,
    const int* __restrict__ img_w, double* __restrict__ scores,
    double* __restrict__ boxes, unsigned long long* __restrict__ keys) {
  __shared__ double sx[4096];
  __shared__ double swl[2880];
  const int b = blockIdx.x >> 6;
  const int ptile = blockIdx.x & 63;
  const int tx = threadIdx.x, ty = threadIdx.y;
  const int tid = ty * 64 + tx;

  double acc[12];
#pragma unroll
  for (int j = 0; j < 12; ++j) acc[j] = 0.0;

  for (int cc = 0; cc < CIN; cc += 64) {
    for (int li = tid; li < 4096; li += 256) {
      int ci = li >> 6, px = li & 63;
      sx[li] = x[((long)b * CIN + cc + ci) * NPIX + ptile * 64 + px];
    }
    for (int li = tid; li < 2880; li += 256) {
      int o = li >> 6, ci = li & 63;
      float wv = (o < 9) ? cls_w[o * CIN + cc + ci] : reg_w[(o - 9) * CIN + cc + ci];
      swl[li] = (double)wv;
    }
    __syncthreads();
#pragma unroll 4
    for (int ci = 0; ci < 64; ++ci) {
      double xv = sx[ci * 64 + tx];
#pragma unroll
      for (int j = 0; j < 12; ++j) {
        int o = ty + 4 * j;
        if (o < 45) acc[j] += swl[o * 64 + ci] * xv;
      }
    }
    __syncthreads();
  }

#pragma unroll
  for (int j = 0; j < 12; ++j) {
    int o = ty + 4 * j;
    if (o < 45) {
      double bv = (o < 9) ? (double)cls_b[o] : (double)reg_b[o - 9];
      swl[o * 64 + tx] = acc[j] + bv;
    }
  }
  __syncthreads();

  const double ih = (double)img_h[0], iw = (double)img_w[0];
  const double sth = ih / (double)FH, stw = iw / (double)FW;
  const double ratios[3] = {0.5, 1.0, 2.0};
  const double sizes[3] = {128.0, 256.0, 512.0};

  for (int it = tid; it < 576; it += 256) {
    int px = it / 9, a = it % 9;
    int p = ptile * 64 + px;
    int hh = p >> 6, ww = p & 63;
    double z = swl[a * 64 + px];
    double score = 1.0 / (1.0 + exp(-z));
    double d0 = swl[(9 + a * 4 + 0) * 64 + px];
    double d1 = swl[(9 + a * 4 + 1) * 64 + px];
    double d2 = swl[(9 + a * 4 + 2) * 64 + px];
    double d3 = swl[(9 + a * 4 + 3) * 64 + px];
    double ratio = ratios[a / 3], size = sizes[a % 3];
    double hr = sqrt(ratio), wr = 1.0 / hr;
    double wsz = wr * size, hsz = hr * size;
    double sxc = (double)ww * stw, syc = (double)hh * sth;
    double ax0 = sxc - wsz * 0.5, ax1 = sxc + wsz * 0.5;
    double ay0 = syc - hsz * 0.5, ay1 = syc + hsz * 0.5;
    double aw = ax1 - ax0, ah = ay1 - ay0;
    double acx = ax0 + 0.5 * aw, acy = ay0 + 0.5 * ah;
    double pcx = d0 * aw + acx, pcy = d1 * ah + acy;
    double pw = exp(d2) * aw, ph = exp(d3) * ah;
    double bx0 = pcx - 0.5 * pw, by0 = pcy - 0.5 * ph;
    double bx1 = pcx + 0.5 * pw, by1 = pcy + 0.5 * ph;
    bx0 = fmin(fmax(bx0, 0.0), iw); bx1 = fmin(fmax(bx1, 0.0), iw);
    by0 = fmin(fmax(by0, 0.0), ih); by1 = fmin(fmax(by1, 0.0), ih);
    long n = (long)p * 9 + a;
    long base = (long)b * NANCH + n;
    boxes[base * 4 + 0] = bx0; boxes[base * 4 + 1] = by0;
    boxes[base * 4 + 2] = bx1; boxes[base * 4 + 3] = by1;
    scores[base] = score;
    unsigned long long bits = (unsigned long long)__double_as_longlong(score);
    keys[(long)b * NPAD + n] =
        ~((bits & 0xFFFFFFFFFFFF0000ull) | (0xFFFFull - (unsigned long long)n));
  }
}

// ---------------- bitonic sort of 4096 u64 in LDS (ascending) ----------------
__device__ inline void bitonic4096(unsigned long long* s, int tid) {
  for (int k = 2; k <= 4096; k <<= 1) {
    for (int j = k >> 1; j > 0; j >>= 1) {
#pragma unroll 2
      for (int t = tid; t < 2048; t += 1024) {
        int i = ((t & ~(j - 1)) << 1) | (t & (j - 1));
        int p = i | j;
        bool up = ((i & k) == 0);
        unsigned long long a = s[i], c = s[p];
        if ((a > c) == up) { s[i] = c; s[p] = a; }
      }
      __syncthreads();
    }
  }
}

__global__ __launch_bounds__(1024) void sort_topk_kernel(
    const unsigned long long* __restrict__ in, unsigned long long* __restrict__ out,
    long in_stride, long out_stride) {
  __shared__ unsigned long long s[4096];
  const int b = blockIdx.y, q = blockIdx.x, tid = threadIdx.x;
  const unsigned long long* ip = in + (long)b * in_stride + (long)q * 4096;
#pragma unroll 4
  for (int l = tid; l < 4096; l += 1024) s[l] = ip[l];
  __syncthreads();
  bitonic4096(s, tid);
  unsigned long long* op = out + (long)b * out_stride + (long)q * 1024;
  op[tid] = s[tid];
}

__global__ __launch_bounds__(1024) void sort_final_kernel(
    const unsigned long long* __restrict__ in, int* __restrict__ sel) {
  __shared__ unsigned long long s[4096];
  const int b = blockIdx.x, tid = threadIdx.x;
  const unsigned long long* ip = in + (long)b * 4096;
#pragma unroll 4
  for (int l = tid; l < 4096; l += 1024) s[l] = ip[l];
  __syncthreads();
  bitonic4096(s, tid);
  if (tid < KPRE) sel[b * 1024 + tid] = (int)(s[tid] & 0xFFFFull);
}

// ---------------- NMS: parallel suppression-mask + single-wave scan ----------
// mask[b][i][w] bit j' = ( iou(box_i, box_{64w+j'}) > 0.7 && 64w+j' > i ).
// Same f64 IoU arithmetic + 1e-9 eps as reference -> bit-identical decisions.
// grid (64 igroups, 8 images), block 256 = 16 i_local x 16 w.
__global__ __launch_bounds__(256) void nms_mask_kernel(
    const double* __restrict__ boxes, const int* __restrict__ sel,
    unsigned long long* __restrict__ mask) {
  __shared__ double X0[KPRE], Y0[KPRE], X1[KPRE], Y1[KPRE], AR[KPRE];
  const int ig = blockIdx.x, b = blockIdx.y, tid = threadIdx.x;
  for (int r = tid; r < KPRE; r += 256) {
    int n = sel[b * 1024 + r];
    const double* bp = boxes + ((long)b * NANCH + n) * 4;
    double x0 = bp[0], y0 = bp[1], x1 = bp[2], y1 = bp[3];
    X0[r] = x0; Y0[r] = y0; X1[r] = x1; Y1[r] = y1;
    AR[r] = (x1 - x0) * (y1 - y0);
  }
  __syncthreads();
  const int i = ig * 16 + (tid >> 4);
  const int w = tid & 15;
  if (i >= KPRE) return;
  const double xi0 = X0[i], yi0 = Y0[i], xi1 = X1[i], yi1 = Y1[i], ai = AR[i];
  unsigned long long m = 0;
#pragma unroll 8
  for (int jj = 0; jj < 64; ++jj) {
    int jo = (jj + w) & 63;          // +w rotation: 16 w-lanes -> 16 bank pairs
    int j = w * 64 + jo;
    if (j < KPRE && j > i) {
      double lx = fmax(xi0, X0[j]), ly = fmax(yi0, Y0[j]);
      double rx = fmin(xi1, X1[j]), ry = fmin(yi1, Y1[j]);
      double ww_ = fmax(rx - lx, 0.0);
      double hh_ = fmax(ry - ly, 0.0);
      double inter = ww_ * hh_;
      double iou = inter / (ai + AR[j] - inter + 1e-9);
      if (iou > 0.7) m |= (1ull << jo);
    }
  }
  mask[((size_t)b * 1024 + i) * 16 + w] = m;
}

// one block per image: stage mask in LDS (125KB <= 160KB), single-wave greedy
// scan (no barriers inside the 1000-iteration loop), emit keep[] ints.
__global__ __launch_bounds__(256) void nms_scan_kernel(
    const unsigned long long* __restrict__ mask, int* __restrict__ keep) {
  __shared__ unsigned long long smask[KPRE * 16];   // 125 KB
  __shared__ unsigned long long skeep[16];
  const int b = blockIdx.x, tid = threadIdx.x;
  const unsigned long long* mb = mask + (size_t)b * 1024 * 16;
  for (int l = tid; l < KPRE * 16; l += 256) smask[l] = mb[(l / 16) * 16 + (l & 15)];
  if (tid < 16) skeep[tid] = ~0ull;
  __syncthreads();
  if (tid < 64) {
    for (int i = 0; i < KPRE; ++i) {
      unsigned long long kw = skeep[i >> 6];        // LDS broadcast
      if ((kw >> (i & 63)) & 1ull) {
        if (tid < 16) skeep[tid] &= ~smask[i * 16 + tid];
      }
    }
  }
  __syncthreads();
  for (int r = tid; r < KPRE; r += 256)
    keep[b * 1024 + r] = (int)((skeep[r >> 6] >> (r & 63)) & 1ull);
}

// ---------------- output: kept-first stable order, zero pad ------------------
__global__ __launch_bounds__(1024) void out_kernel(
    const double* __restrict__ boxes, const double* __restrict__ scores,
    const int* __restrict__ sel, const int* __restrict__ keep,
    float* __restrict__ out) {
  const int b = blockIdx.x, tid = threadIdx.x;
  int kv = (tid < KPRE) ? keep[b * 1024 + tid] : 0;
  unsigned long long m = __ballot(kv != 0);
  int lane = tid & 63, wid = tid >> 6;
  __shared__ int wcnt[16], woff[16], tot;
  if (lane == 0) wcnt[wid] = __popcll(m);
  __syncthreads();
  if (tid == 0) {
    int s = 0;
    for (int w2 = 0; w2 < 16; ++w2) { woff[w2] = s; s += wcnt[w2]; }
    tot = s;
  }
  __syncthreads();
  int before = __popcll(m & ((1ull << lane) - 1ull));
  int pref = woff[wid] + before;
  if (tid < KPRE) {
    int pos = kv ? pref : (tot + (tid - pref));
    if (pos < KPOST) {
      float* o = out + ((long)b * KPOST + pos) * 5;
      if (kv) {
        int n = sel[b * 1024 + tid];
        const double* bp = boxes + ((long)b * NANCH + n) * 4;
        o[0] = (float)bp[0]; o[1] = (float)bp[1];
        o[2] = (float)bp[2]; o[3] = (float)bp[3];
        o[4] = (float)scores[(long)b * NANCH + n];
      } else {
        o[0] = 0.f; o[1] = 0.f; o[2] = 0.f; o[3] = 0.f; o[4] = 0.f;
      }
    }
  }
}

extern "C" void kernel_launch(void* const* d_in, const int* in_sizes, int n_in,
                              void* d_out, int out_size, void* d_ws, size_t ws_size,
                              hipStream_t stream) {
  const float* fm     = (const float*)d_in[0];
  const float* base_w = (const float*)d_in[1];
  const float* base_b = (const float*)d_in[2];
  const float* cls_w  = (const float*)d_in[3];
  const float* cls_b  = (const float*)d_in[4];
  const float* reg_w  = (const float*)d_in[5];
  const float* reg_b  = (const float*)d_in[6];
  const int* img_h    = (const int*)d_in[7];
  const int* img_w    = (const int*)d_in[8];
  float* out          = (float*)d_out;

  if (ws_size < WS_NEEDED) return;  // visible failure rather than corruption

  char* ws = (char*)d_ws;
  double* x                 = (double*)(ws + OFF_X);
  double* scores            = (double*)(ws + OFF_SCORES);
  double* boxes             = (double*)(ws + OFF_BOXES);
  unsigned long long* keys  = (unsigned long long*)(ws + OFF_KEYS);
  unsigned long long* buf1  = (unsigned long long*)(ws + OFF_BUF1);
  unsigned long long* buf2  = (unsigned long long*)(ws + OFF_BUF2);
  int* sel                  = (int*)(ws + OFF_SEL);
  int* keep                 = (int*)(ws + OFF_KEEP);
  unsigned long long* mask  = (unsigned long long*)(ws + OFF_MASK);  // x region, dead after heads

  // pad keys (anchors 36864..65535) and buf1 (chunks 9..15) with worst key
  hipMemsetAsync(ws + OFF_KEYS, 0xFF, 4194304ull + 1048576ull, stream);

  if (ws_size >= WS_WINO_FULL) {
    // Winograd, full image per launch-set (T=1024)
    double* U = (double*)(ws + WOFF_U);
    double* V = (double*)(ws + WOFF_V);
    double* M = (double*)(ws + WOFF_V + 67108864ull);
    wino_wt_kernel<<<dim3(1024), dim3(256), 0, stream>>>(base_w, U);
    for (int b = 0; b < BS; ++b) {
      wino_in_kernel<1024><<<dim3(2048), dim3(256), 0, stream>>>(fm, V, b, 0);
      wino_gemm_kernel<1024><<<dim3(8, 8, 16), dim3(256), 0, stream>>>(U, V, M);
      wino_out_kernel<1024><<<dim3(2048), dim3(256), 0, stream>>>(M, base_b, x, b, 0);
    }
  } else if (ws_size >= WS_WINO_HALF) {
    // Winograd, half-image chunks (T=512)
    double* U = (double*)(ws + WOFF_U);
    double* V = (double*)(ws + WOFF_V);
    double* M = (double*)(ws + WOFF_V + 33554432ull);
    wino_wt_kernel<<<dim3(1024), dim3(256), 0, stream>>>(base_w, U);
    for (int b = 0; b < BS; ++b) {
      for (int t0 = 0; t0 < 1024; t0 += 512) {
        wino_in_kernel<512><<<dim3(1024), dim3(256), 0, stream>>>(fm, V, b, t0);
        wino_gemm_kernel<512><<<dim3(8, 4, 16), dim3(256), 0, stream>>>(U, V, M);
        wino_out_kernel<512><<<dim3(1024), dim3(256), 0, stream>>>(M, base_b, x, b, t0);
      }
    }
  } else {
    // direct implicit-GEMM conv (R6 path)
    conv_mfma_kernel<<<dim3(8, 32, 8), dim3(256), 0, stream>>>(fm, base_w, base_b, x);
  }

  heads_kernel<<<dim3(512), dim3(64, 4), 0, stream>>>(
      x, cls_w, cls_b, reg_w, reg_b, img_h, img_w, scores, boxes, keys);
  sort_topk_kernel<<<dim3(9, 8), dim3(1024), 0, stream>>>(keys, buf1, 65536, 16384);
  sort_topk_kernel<<<dim3(4, 8), dim3(1024), 0, stream>>>(buf1, buf2, 16384, 4096);
  sort_final_kernel<<<dim3(8), dim3(1024), 0, stream>>>(buf2, sel);
  nms_mask_kernel<<<dim3(64, 8), dim3(256), 0, stream>>>(boxes, sel, mask);
  nms_scan_kernel<<<dim3(8), dim3(256), 0, stream>>>(mask, keep);
  out_kernel<<<dim3(8), dim3(1024), 0, stream>>>(boxes, scores, sel, keep, out);
}

// Round 10
// 1777.439 us; speedup vs baseline: 1.7235x; 1.1171x over previous
//
#include <hip/hip_runtime.h>
#include <math.h>

// RPNHead: conv3x3(512->512)+ReLU -> cls(9)/reg(36) 1x1 -> sigmoid/box-decode
// -> per-image exact top-1000 (by f64 score, index tie-break) -> greedy NMS
// -> [8,300,5] f32 output (kept-first stable order, zero-padded).
//
// Score/box pipeline in fp64 so top-k ordering and NMS decisions match a
// float64 numpy reference exactly (adjacent-score spacing ~5e-5..5e-8 >> f64
// noise ~1e-16; f32 would swap ranks -> wrong rows -> absmax ~1000).
//
// R2-R4: conv as implicit-GEMM on v_mfma_f64_16x16x4_f64; probe-decoded C/D
//        layout (gfx950 f64 MFMA mapping differs from CDNA2 docs).
// R5: f32 LDS, stride-80 pad, dbuf+T14, hoisted addressing. 2647us, 81%.
// R6: occupancy 2->3+ waves/SIMD + setprio. conv 2530us, MfmaUtil 85.5%.
// R7: Winograd full-image tier never ran => ws < 319.4MB.
// R8: tile-chunked Winograd T=512 (252.2MB): total 2272us. ws in [252.2,319.4).
// R9: NMS bitmask+single-wave-scan: 2272->1986us. New top: heads 280us,
//     VALUBusy 9.7%/HBM 3.6%/Mfma 0 -- LDS-latency-bound scalar GEMM.
// R10: heads -> f64 MFMA implicit GEMM (48oc x 64px block tile, KC=16,
//      conv-proven reg-prefetch dbuf + probe-decoded D). Logits to LDS,
//      then the identical decode/box/key code (bias at logit write) ->
//      bit-identical outputs. Floor: max(134MB/6.3TBps, 1.5e9/78.6TF) ~21us.

typedef double f64x4 __attribute__((ext_vector_type(4)));
typedef double f64x2 __attribute__((ext_vector_type(2)));

#define BS 8
#define CIN 512
#define COUT 512
#define FH 64
#define FW 64
#define NA 9
#define NPIX (FH*FW)          // 4096
#define NANCH (NPIX*NA)       // 36864
#define NPAD 65536
#define KPRE 1000
#define KPOST 300

// ---- workspace layout (bytes) ----
#define OFF_X      0ull                                   // 8*512*4096 f64 = 134217728
#define OFF_SCORES (OFF_X + 134217728ull)                 // 8*36864 f64    = 2359296
#define OFF_BOXES  (OFF_SCORES + 2359296ull)              // 8*36864*4 f64  = 9437184
#define OFF_KEYS   (OFF_BOXES + 9437184ull)               // 8*65536 u64    = 4194304
#define OFF_BUF1   (OFF_KEYS + 4194304ull)                // 8*16*1024 u64  = 1048576
#define OFF_BUF2   (OFF_BUF1 + 1048576ull)                // 8*4*1024 u64   = 262144
#define OFF_SEL    (OFF_BUF2 + 262144ull)                 // 8*1024 i32     = 32768
#define OFF_KEEP   (OFF_SEL + 32768ull)                   // 8*1024 i32     = 32768
#define WS_NEEDED  (OFF_KEEP + 32768ull)                  // 151584768
// NMS suppression-mask matrix: reuses OFF_X (x dead after heads).
#define OFF_MASK   OFF_X                                  // 8*1024*16 u64  = 1048576
// Winograd extension
#define WOFF_U        WS_NEEDED                           // 16*512*512 f64 = 33554432
#define WOFF_V        (WOFF_U + 33554432ull)
#define WS_WINO_FULL  (WOFF_V + 67108864ull + 67108864ull)  // 319356928
#define WS_WINO_HALF  (WOFF_V + 33554432ull + 33554432ull)  // 252248064

// =================== R6 direct-conv path (fallback) ==========================
#define SW_STRIDE 80
#define SW_WORDS  (36 * SW_STRIDE)
#define SI_RSTRIDE 80
#define SI_CSTRIDE 320
#define BUF_WORDS (SW_WORDS + 4 * SI_CSTRIDE)

__device__ __forceinline__ void conv_compute(
    const float* __restrict__ sWp, const float* __restrict__ sIp,
    const int* __restrict__ boff, f64x4 acc[2][4]) {
#pragma unroll
  for (int k0s = 0; k0s < 9; ++k0s) {
    double a0 = (double)sWp[k0s * 4 * SW_STRIDE];
    double a1 = (double)sWp[k0s * 4 * SW_STRIDE + 16];
    const float* bp = sIp + boff[k0s];
    double b0 = (double)bp[0];
    double b1 = (double)bp[16];
    double b2 = (double)bp[32];
    double b3 = (double)bp[48];
    acc[0][0] = __builtin_amdgcn_mfma_f64_16x16x4f64(a0, b0, acc[0][0], 0, 0, 0);
    acc[0][1] = __builtin_amdgcn_mfma_f64_16x16x4f64(a0, b1, acc[0][1], 0, 0, 0);
    acc[0][2] = __builtin_amdgcn_mfma_f64_16x16x4f64(a0, b2, acc[0][2], 0, 0, 0);
    acc[0][3] = __builtin_amdgcn_mfma_f64_16x16x4f64(a0, b3, acc[0][3], 0, 0, 0);
    acc[1][0] = __builtin_amdgcn_mfma_f64_16x16x4f64(a1, b0, acc[1][0], 0, 0, 0);
    acc[1][1] = __builtin_amdgcn_mfma_f64_16x16x4f64(a1, b1, acc[1][1], 0, 0, 0);
    acc[1][2] = __builtin_amdgcn_mfma_f64_16x16x4f64(a1, b2, acc[1][2], 0, 0, 0);
    acc[1][3] = __builtin_amdgcn_mfma_f64_16x16x4f64(a1, b3, acc[1][3], 0, 0, 0);
  }
}

__global__ __launch_bounds__(256, 3) void conv_mfma_kernel(
    const float* __restrict__ fm, const float* __restrict__ W,
    const float* __restrict__ bias, double* __restrict__ x) {
  __shared__ float sbuf[2 * BUF_WORDS];
  const int ocb = blockIdx.x, rp = blockIdx.y, b = blockIdx.z;
  const int h0 = rp * 2;
  const int oc0 = ocb * 64;
  const int tid = threadIdx.x;
  const int wid = tid >> 6, l = tid & 63;
  const int q = l >> 4, r16 = l & 15;
  const int wm = wid >> 1, wn = wid & 1;

  const int wo = tid >> 2, wseg = tid & 3;
  const float* wbase = W + (size_t)(oc0 + wo) * 4608 + wseg * 9;
  const int wlds0 = (wseg * 9) * SW_STRIDE + wo;

  const float* fmb = fm + (size_t)b * CIN * NPIX;
  int ioff[5];
  int idls[5];
  bool sact[5], lact[5];
#pragma unroll
  for (int s = 0; s < 5; ++s) {
    int li = tid + 256 * s;
    sact[s] = li < 1056;
    int li_c = sact[s] ? li : 0;
    int c = li_c / 264, rem = li_c % 264, r = rem / 66, col = rem % 66;
    int gy = h0 - 1 + r, gx = col - 1;
    lact[s] = sact[s] && gy >= 0 && gy < FH && gx >= 0 && gx < FW;
    ioff[s] = lact[s] ? (c * NPIX + gy * FW + gx) : 0;
    idls[s] = SW_WORDS + c * SI_CSTRIDE + r * SI_RSTRIDE + col;
  }

  const int apos = q * SW_STRIDE + wm * 32 + r16;
  const int ipos = SW_WORDS + wn * SI_RSTRIDE + r16;
  int boff[9];
#pragma unroll
  for (int k0s = 0; k0s < 9; ++k0s) {
    int k = k0s * 4 + q;
    int c = k / 9, t = k - 9 * c;
    int dy = t / 3, dx = t - 3 * dy;
    boff[k0s] = c * SI_CSTRIDE + dy * SI_RSTRIDE + dx;
  }

  f64x4 acc[2][4];
#pragma unroll
  for (int tm = 0; tm < 2; ++tm)
#pragma unroll
    for (int tn = 0; tn < 4; ++tn)
#pragma unroll
      for (int v = 0; v < 4; ++v) acc[tm][tn][v] = 0.0;

  float wreg[9], ireg[5];

#define LOAD_REGS(t) do {                                            \
    const int cc_ = 4 * (t);                                         \
    _Pragma("unroll")                                                \
    for (int j = 0; j < 9; ++j) wreg[j] = wbase[cc_ * 9 + j];        \
    _Pragma("unroll")                                                \
    for (int s = 0; s < 5; ++s)                                      \
      ireg[s] = lact[s] ? fmb[(size_t)(ioff[s] + cc_ * NPIX)] : 0.f; \
  } while (0)

#define WRITE_LDS(base) do {                                         \
    _Pragma("unroll")                                                \
    for (int j = 0; j < 9; ++j) (base)[wlds0 + j * SW_STRIDE] = wreg[j]; \
    _Pragma("unroll")                                                \
    for (int s = 0; s < 5; ++s)                                      \
      if (sact[s]) (base)[idls[s]] = ireg[s];                        \
  } while (0)

  float* buf0 = sbuf;
  float* buf1 = sbuf + BUF_WORDS;

  LOAD_REGS(0);
  WRITE_LDS(buf0);
  __syncthreads();

  for (int tt = 0; tt < 64; ++tt) {
    const int t1 = 2 * tt + 1;
    LOAD_REGS(t1);
    __builtin_amdgcn_s_setprio(1);
    conv_compute(buf0 + apos, buf0 + ipos, boff, acc);
    __builtin_amdgcn_s_setprio(0);
    WRITE_LDS(buf1);
    __syncthreads();
    const int t2 = (t1 + 1 < 128) ? t1 + 1 : 127;
    LOAD_REGS(t2);
    __builtin_amdgcn_s_setprio(1);
    conv_compute(buf1 + apos, buf1 + ipos, boff, acc);
    __builtin_amdgcn_s_setprio(0);
    WRITE_LDS(buf0);
    __syncthreads();
  }

  int prow[4], pcol[4];
  {
    f64x4 probe = {0.0, 0.0, 0.0, 0.0};
    double pa = (q == 0) ? (double)r16 : ((q == 1) ? 1.0 : 0.0);
    double pb = (q == 0) ? 1.0 : ((q == 1) ? (double)(16 * r16) : 0.0);
    probe = __builtin_amdgcn_mfma_f64_16x16x4f64(pa, pb, probe, 0, 0, 0);
#pragma unroll
    for (int v = 0; v < 4; ++v) {
      int val = (int)(probe[v] + 0.5);
      prow[v] = val & 15;
      pcol[v] = (val >> 4) & 15;
    }
  }

#pragma unroll
  for (int tm = 0; tm < 2; ++tm) {
#pragma unroll
    for (int v = 0; v < 4; ++v) {
      const int oc = oc0 + wm * 32 + tm * 16 + prow[v];
      const double bv = (double)bias[oc];
      const int h = h0 + wn;
#pragma unroll
      for (int tn = 0; tn < 4; ++tn) {
        const int w = tn * 16 + pcol[v];
        double val = acc[tm][tn][v] + bv;
        val = val > 0.0 ? val : 0.0;
        x[(size_t)(b * COUT + oc) * NPIX + h * FW + w] = val;
      }
    }
  }
#undef LOAD_REGS
#undef WRITE_LDS
}

// =================== Winograd F(2x2,3x3) path (tile-chunked) =================
__global__ __launch_bounds__(256) void wino_wt_kernel(
    const float* __restrict__ W, double* __restrict__ U) {
  const int id = blockIdx.x * 256 + threadIdx.x;   // 262144
  const int oc = id >> 9, c = id & 511;
  const float* g = W + (size_t)(oc * CIN + c) * 9;
  double g0[3], g1[3], g2[3];
#pragma unroll
  for (int j = 0; j < 3; ++j) {
    g0[j] = (double)g[j];
    g1[j] = (double)g[3 + j];
    g2[j] = (double)g[6 + j];
  }
  double T[4][3];
#pragma unroll
  for (int j = 0; j < 3; ++j) {
    T[0][j] = g0[j];
    T[1][j] = 0.5 * (g0[j] + g1[j] + g2[j]);
    T[2][j] = 0.5 * (g0[j] - g1[j] + g2[j]);
    T[3][j] = g2[j];
  }
  double* Ub = U + (size_t)c * 512 + oc;   // + pos*262144
#pragma unroll
  for (int xi = 0; xi < 4; ++xi) {
    double u0 = T[xi][0];
    double u1 = 0.5 * (T[xi][0] + T[xi][1] + T[xi][2]);
    double u2 = 0.5 * (T[xi][0] - T[xi][1] + T[xi][2]);
    double u3 = T[xi][2];
    Ub[(size_t)(xi * 4 + 0) * 262144] = u0;
    Ub[(size_t)(xi * 4 + 1) * 262144] = u1;
    Ub[(size_t)(xi * 4 + 2) * 262144] = u2;
    Ub[(size_t)(xi * 4 + 3) * 262144] = u3;
  }
}

template <int T>
__global__ __launch_bounds__(256) void wino_in_kernel(
    const float* __restrict__ fm, double* __restrict__ V, int b, int t0) {
  const int id = blockIdx.x * 256 + threadIdx.x;   // 512*T
  const int c = id / T, rem = id % T;
  const int tyx = t0 + rem;
  const int ty = tyx >> 5, tx = tyx & 31;
  const float* src = fm + (size_t)(b * CIN + c) * NPIX;
  const int y0 = 2 * ty - 1, x0 = 2 * tx - 1;
  double d[4][4];
#pragma unroll
  for (int r = 0; r < 4; ++r) {
    int y = y0 + r;
#pragma unroll
    for (int s = 0; s < 4; ++s) {
      int xx = x0 + s;
      d[r][s] = (y >= 0 && y < FH && xx >= 0 && xx < FW)
                    ? (double)src[y * FW + xx] : 0.0;
    }
  }
  double Z[4][4];
#pragma unroll
  for (int s = 0; s < 4; ++s) {
    Z[0][s] = d[0][s] - d[2][s];
    Z[1][s] = d[1][s] + d[2][s];
    Z[2][s] = d[2][s] - d[1][s];
    Z[3][s] = d[1][s] - d[3][s];
  }
  double* Vb = V + (size_t)c * T + rem;   // + pos*512*T
#pragma unroll
  for (int xi = 0; xi < 4; ++xi) {
    double v0 = Z[xi][0] - Z[xi][2];
    double v1 = Z[xi][1] + Z[xi][2];
    double v2 = Z[xi][2] - Z[xi][1];
    double v3 = Z[xi][1] - Z[xi][3];
    Vb[(size_t)(xi * 4 + 0) * 512 * T] = v0;
    Vb[(size_t)(xi * 4 + 1) * 512 * T] = v1;
    Vb[(size_t)(xi * 4 + 2) * 512 * T] = v2;
    Vb[(size_t)(xi * 4 + 3) * 512 * T] = v3;
  }
}

#define WSU_STRIDE 72
#define WSV_STRIDE 136
#define WSU_WORDS  (8 * WSU_STRIDE)              // 576
#define WBUF_WORDS (WSU_WORDS + 8 * WSV_STRIDE)  // 1664 f64 = 13312 B

__device__ __forceinline__ void wino_compute(
    const double* __restrict__ sA, const double* __restrict__ sB,
    f64x4 acc[2][4]) {
#pragma unroll
  for (int kg = 0; kg < 2; ++kg) {
    double a0 = sA[kg * 4 * WSU_STRIDE];
    double a1 = sA[kg * 4 * WSU_STRIDE + 16];
    const double* bp = sB + kg * 4 * WSV_STRIDE;
    double b0 = bp[0];
    double b1 = bp[16];
    double b2 = bp[32];
    double b3 = bp[48];
    acc[0][0] = __builtin_amdgcn_mfma_f64_16x16x4f64(a0, b0, acc[0][0], 0, 0, 0);
    acc[0][1] = __builtin_amdgcn_mfma_f64_16x16x4f64(a0, b1, acc[0][1], 0, 0, 0);
    acc[0][2] = __builtin_amdgcn_mfma_f64_16x16x4f64(a0, b2, acc[0][2], 0, 0, 0);
    acc[0][3] = __builtin_amdgcn_mfma_f64_16x16x4f64(a0, b3, acc[0][3], 0, 0, 0);
    acc[1][0] = __builtin_amdgcn_mfma_f64_16x16x4f64(a1, b0, acc[1][0], 0, 0, 0);
    acc[1][1] = __builtin_amdgcn_mfma_f64_16x16x4f64(a1, b1, acc[1][1], 0, 0, 0);
    acc[1][2] = __builtin_amdgcn_mfma_f64_16x16x4f64(a1, b2, acc[1][2], 0, 0, 0);
    acc[1][3] = __builtin_amdgcn_mfma_f64_16x16x4f64(a1, b3, acc[1][3], 0, 0, 0);
  }
}

template <int T>
__global__ __launch_bounds__(256, 3) void wino_gemm_kernel(
    const double* __restrict__ U, const double* __restrict__ V,
    double* __restrict__ M) {
  __shared__ double sbuf[2 * WBUF_WORDS];
  const int ocb = blockIdx.x, tb = blockIdx.y, pos = blockIdx.z;
  const int oc0 = ocb * 64, t0 = tb * 128;
  const int tid = threadIdx.x;
  const int wid = tid >> 6, l = tid & 63;
  const int q = l >> 4, r16 = l & 15;
  const int wm = wid >> 1, wn = wid & 1;   // 2(M) x 2(N) waves

  const int ka = tid >> 5;                 // 0..7
  const int oc2 = (tid & 31) * 2;          // A: 2 f64/thread
  const int t4 = (tid & 31) * 4;           // B: 4 f64/thread
  const double* uSrc = U + (size_t)pos * 262144 + (size_t)ka * 512 + oc0 + oc2;
  const double* vSrc = V + (size_t)pos * 512 * T + (size_t)ka * T + t0 + t4;
  const int ua_lds = ka * WSU_STRIDE + oc2;
  const int vb_lds = WSU_WORDS + ka * WSV_STRIDE + t4;

  const int apos = q * WSU_STRIDE + wm * 32 + r16;
  const int bpos = WSU_WORDS + q * WSV_STRIDE + wn * 64 + r16;

  f64x4 acc[2][4];
#pragma unroll
  for (int tm = 0; tm < 2; ++tm)
#pragma unroll
    for (int tn = 0; tn < 4; ++tn)
#pragma unroll
      for (int v = 0; v < 4; ++v) acc[tm][tn][v] = 0.0;

  f64x2 ra, rb0, rb1;

#define WLOAD(t) do {                                                  \
    const size_t cc_ = 8 * (size_t)(t);                                \
    ra  = *(const f64x2*)(uSrc + cc_ * 512);                           \
    rb0 = *(const f64x2*)(vSrc + cc_ * T);                             \
    rb1 = *(const f64x2*)(vSrc + cc_ * T + 2);                         \
  } while (0)

#define WSTORE(base) do {                                              \
    (base)[ua_lds] = ra[0]; (base)[ua_lds + 1] = ra[1];                \
    (base)[vb_lds] = rb0[0]; (base)[vb_lds + 1] = rb0[1];              \
    (base)[vb_lds + 2] = rb1[0]; (base)[vb_lds + 3] = rb1[1];          \
  } while (0)

  double* buf0 = sbuf;
  double* buf1 = sbuf + WBUF_WORDS;

  WLOAD(0);
  WSTORE(buf0);
  __syncthreads();

  for (int tt = 0; tt < 32; ++tt) {
    const int t1 = 2 * tt + 1;
    WLOAD(t1);
    __builtin_amdgcn_s_setprio(1);
    wino_compute(buf0 + apos, buf0 + bpos, acc);
    __builtin_amdgcn_s_setprio(0);
    WSTORE(buf1);
    __syncthreads();
    const int t2 = (t1 + 1 < 64) ? t1 + 1 : 63;
    WLOAD(t2);
    __builtin_amdgcn_s_setprio(1);
    wino_compute(buf1 + apos, buf1 + bpos, acc);
    __builtin_amdgcn_s_setprio(0);
    WSTORE(buf0);
    __syncthreads();
  }

  int prow[4], pcol[4];
  {
    f64x4 probe = {0.0, 0.0, 0.0, 0.0};
    double pa = (q == 0) ? (double)r16 : ((q == 1) ? 1.0 : 0.0);
    double pb = (q == 0) ? 1.0 : ((q == 1) ? (double)(16 * r16) : 0.0);
    probe = __builtin_amdgcn_mfma_f64_16x16x4f64(pa, pb, probe, 0, 0, 0);
#pragma unroll
    for (int v = 0; v < 4; ++v) {
      int val = (int)(probe[v] + 0.5);
      prow[v] = val & 15;
      pcol[v] = (val >> 4) & 15;
    }
  }

#pragma unroll
  for (int tm = 0; tm < 2; ++tm) {
#pragma unroll
    for (int v = 0; v < 4; ++v) {
      const int oc = oc0 + wm * 32 + tm * 16 + prow[v];
#pragma unroll
      for (int tn = 0; tn < 4; ++tn) {
        const int col = wn * 64 + tn * 16 + pcol[v];
        M[(size_t)pos * 512 * T + (size_t)oc * T + t0 + col] = acc[tm][tn][v];
      }
    }
  }
#undef WLOAD
#undef WSTORE
}

template <int T>
__global__ __launch_bounds__(256) void wino_out_kernel(
    const double* __restrict__ M, const float* __restrict__ bias,
    double* __restrict__ x, int b, int t0) {
  const int id = blockIdx.x * 256 + threadIdx.x;   // 512*T
  const int oc = id / T, rem = id % T;
  const int tyx = t0 + rem;
  const int ty = tyx >> 5, tx = tyx & 31;
  double m[4][4];
#pragma unroll
  for (int xi = 0; xi < 4; ++xi)
#pragma unroll
    for (int nu = 0; nu < 4; ++nu)
      m[xi][nu] = M[(size_t)(xi * 4 + nu) * 512 * T + (size_t)oc * T + rem];
  double P[2][4];
#pragma unroll
  for (int nu = 0; nu < 4; ++nu) {
    P[0][nu] = m[0][nu] + m[1][nu] + m[2][nu];
    P[1][nu] = m[1][nu] - m[2][nu] - m[3][nu];
  }
  const double bv = (double)bias[oc];
  double* xb = x + (size_t)(b * COUT + oc) * NPIX + (2 * ty) * FW + 2 * tx;
#pragma unroll
  for (int i = 0; i < 2; ++i) {
    double y0 = P[i][0] + P[i][1] + P[i][2] + bv;
    double y1 = P[i][1] - P[i][2] - P[i][3] + bv;
    y0 = y0 > 0.0 ? y0 : 0.0;
    y1 = y1 > 0.0 ? y1 : 0.0;
    xb[i * FW] = y0;
    xb[i * FW + 1] = y1;
  }
}

// ---------------- heads: f64 MFMA GEMM (48oc x 64px tiles) + decode ----------
// out[o][px] = sum_c Wh[o][c] x[b][c][px]; M=45(pad 48), N=4096, K=512.
// grid (64 pxb, 8 b), block 256 = 4 waves; wave wn owns px [wn*16, wn*16+16),
// computes 3 m-tiles. KC=16 -> 32 chunks, reg-prefetch dbuf (conv-proven).
#define HX_STRIDE 72                       // sx [16][72]
#define HW_STRIDE 52                       // sw [16][52]
#define HSX_WORDS (16 * HX_STRIDE)         // 1152
#define HBUF_WORDS (HSX_WORDS + 16 * HW_STRIDE)  // 1984

__device__ __forceinline__ void heads_compute(
    const double* __restrict__ sA, const double* __restrict__ sB,
    f64x4 acc[3]) {
#pragma unroll
  for (int k0s = 0; k0s < 4; ++k0s) {
    double a0 = sA[k0s * 4 * HW_STRIDE];
    double a1 = sA[k0s * 4 * HW_STRIDE + 16];
    double a2 = sA[k0s * 4 * HW_STRIDE + 32];
    double b0 = sB[k0s * 4 * HX_STRIDE];
    acc[0] = __builtin_amdgcn_mfma_f64_16x16x4f64(a0, b0, acc[0], 0, 0, 0);
    acc[1] = __builtin_amdgcn_mfma_f64_16x16x4f64(a1, b0, acc[1], 0, 0, 0);
    acc[2] = __builtin_amdgcn_mfma_f64_16x16x4f64(a2, b0, acc[2], 0, 0, 0);
  }
}

__global__ __launch_bounds__(256) void heads_mfma_kernel(
    const double* __restrict__ x, const float* __restrict__ cls_w,
    const float* __restrict__ cls_b, const float* __restrict__ reg_w,
    const float* __restrict__ reg_b, const int* __restrict__ img_h,
    const int* __restrict__ img_w, double* __restrict__ scores,
    double* __restrict__ boxes, unsigned long long* __restrict__ keys) {
  __shared__ double sh[2 * HBUF_WORDS];    // dbuf staging; logits reuse (3240<3968)
  const int pxb = blockIdx.x, b = blockIdx.y;
  const int tid = threadIdx.x;
  const int wid = tid >> 6, l = tid & 63;
  const int q = l >> 4, r16 = l & 15;
  const int wn = wid;                      // wave's 16-px slice

  // staging maps (loop-invariant). x: 4 slots (16k x 64px); W: 3 slots (16k x 48o)
  const double* xbase = x + (size_t)b * CIN * NPIX + pxb * 64;
  int sxk[4], sxp[4];
#pragma unroll
  for (int s = 0; s < 4; ++s) {
    int i = tid + 256 * s;
    sxk[s] = i >> 6; sxp[s] = i & 63;
  }
  int swk[3], swo[3];
#pragma unroll
  for (int s = 0; s < 3; ++s) {
    int i = tid + 256 * s;                 // < 768 always
    swk[s] = i / 48; swo[s] = i % 48;
  }

  const int aposh = HSX_WORDS + q * HW_STRIDE + r16;  // + k0s*4*HW + mt*16
  const int bposh = q * HX_STRIDE + wn * 16 + r16;    // + k0s*4*HX

  f64x4 acc[3];
#pragma unroll
  for (int mt = 0; mt < 3; ++mt)
#pragma unroll
    for (int v = 0; v < 4; ++v) acc[mt][v] = 0.0;

  double xr[4], wr[3];

#define HLOAD(t) do {                                                    \
    const int cc_ = 16 * (t);                                            \
    _Pragma("unroll")                                                    \
    for (int s = 0; s < 4; ++s)                                          \
      xr[s] = xbase[(size_t)(cc_ + sxk[s]) * NPIX + sxp[s]];             \
    _Pragma("unroll")                                                    \
    for (int s = 0; s < 3; ++s) {                                        \
      int o = swo[s], k = cc_ + swk[s];                                  \
      wr[s] = (o < 9) ? (double)cls_w[o * CIN + k]                       \
            : (o < 45) ? (double)reg_w[(o - 9) * CIN + k] : 0.0;         \
    }                                                                    \
  } while (0)

#define HSTORE(base) do {                                                \
    _Pragma("unroll")                                                    \
    for (int s = 0; s < 4; ++s) (base)[sxk[s] * HX_STRIDE + sxp[s]] = xr[s]; \
    _Pragma("unroll")                                                    \
    for (int s = 0; s < 3; ++s)                                          \
      (base)[HSX_WORDS + swk[s] * HW_STRIDE + swo[s]] = wr[s];           \
  } while (0)

  double* buf0 = sh;
  double* buf1 = sh + HBUF_WORDS;

  HLOAD(0);
  HSTORE(buf0);
  __syncthreads();

  for (int tt = 0; tt < 16; ++tt) {
    const int t1 = 2 * tt + 1;
    HLOAD(t1);
    __builtin_amdgcn_s_setprio(1);
    heads_compute(buf0 + aposh, buf0 + bposh, acc);
    __builtin_amdgcn_s_setprio(0);
    HSTORE(buf1);
    __syncthreads();
    const int t2 = (t1 + 1 < 32) ? t1 + 1 : 31;
    HLOAD(t2);
    __builtin_amdgcn_s_setprio(1);
    heads_compute(buf1 + aposh, buf1 + bposh, acc);
    __builtin_amdgcn_s_setprio(0);
    HSTORE(buf0);
    __syncthreads();
  }

  // probe-decoded D mapping
  int prow[4], pcol[4];
  {
    f64x4 probe = {0.0, 0.0, 0.0, 0.0};
    double pa = (q == 0) ? (double)r16 : ((q == 1) ? 1.0 : 0.0);
    double pb = (q == 0) ? 1.0 : ((q == 1) ? (double)(16 * r16) : 0.0);
    probe = __builtin_amdgcn_mfma_f64_16x16x4f64(pa, pb, probe, 0, 0, 0);
#pragma unroll
    for (int v = 0; v < 4; ++v) {
      int val = (int)(probe[v] + 0.5);
      prow[v] = val & 15;
      pcol[v] = (val >> 4) & 15;
    }
  }

  // write logits (+bias) to LDS [45][HX_STRIDE] (reuses staging; all compute done)
  double* slog = sh;
#pragma unroll
  for (int mt = 0; mt < 3; ++mt) {
#pragma unroll
    for (int v = 0; v < 4; ++v) {
      const int o = mt * 16 + prow[v];
      if (o < 45) {
        double bv = (o < 9) ? (double)cls_b[o] : (double)reg_b[o - 9];
        slog[o * HX_STRIDE + wn * 16 + pcol[v]] = acc[mt][v] + bv;
      }
    }
  }
  __syncthreads();

  // decode: identical math to original heads kernel
  const double ih = (double)img_h[0], iw = (double)img_w[0];
  const double sth = ih / (double)FH, stw = iw / (double)FW;
  const double ratios[3] = {0.5, 1.0, 2.0};
  const double sizes[3] = {128.0, 256.0, 512.0};

  for (int it = tid; it < 576; it += 256) {
    int px = it / 9, a = it % 9;
    int p = pxb * 64 + px;
    int hh = p >> 6, ww = p & 63;
    double z = slog[a * HX_STRIDE + px];
    double score = 1.0 / (1.0 + exp(-z));
    double d0 = slog[(9 + a * 4 + 0) * HX_STRIDE + px];
    double d1 = slog[(9 + a * 4 + 1) * HX_STRIDE + px];
    double d2 = slog[(9 + a * 4 + 2) * HX_STRIDE + px];
    double d3 = slog[(9 + a * 4 + 3) * HX_STRIDE + px];
    double ratio = ratios[a / 3], size = sizes[a % 3];
    double hr = sqrt(ratio), wr_ = 1.0 / hr;
    double wsz = wr_ * size, hsz = hr * size;
    double sxc = (double)ww * stw, syc = (double)hh * sth;
    double ax0 = sxc - wsz * 0.5, ax1 = sxc + wsz * 0.5;
    double ay0 = syc - hsz * 0.5, ay1 = syc + hsz * 0.5;
    double aw = ax1 - ax0, ah = ay1 - ay0;
    double acx = ax0 + 0.5 * aw, acy = ay0 + 0.5 * ah;
    double pcx = d0 * aw + acx, pcy = d1 * ah + acy;
    double pw = exp(d2) * aw, ph = exp(d3) * ah;
    double bx0 = pcx - 0.5 * pw, by0 = pcy - 0.5 * ph;
    double bx1 = pcx + 0.5 * pw, by1 = pcy + 0.5 * ph;
    bx0 = fmin(fmax(bx0, 0.0), iw); bx1 = fmin(fmax(bx1, 0.0), iw);
    by0 = fmin(fmax(by0, 0.0), ih); by1 = fmin(fmax(by1, 0.0), ih);
    long n = (long)p * 9 + a;
    long base = (long)b * NANCH + n;
    boxes[base * 4 + 0] = bx0; boxes[base * 4 + 1] = by0;
    boxes[base * 4 + 2] = bx1; boxes[base * 4 + 3] = by1;
    scores[base] = score;
    unsigned long long bits = (unsigned long long)__double_as_longlong(score);
    keys[(long)b * NPAD + n] =
        ~((bits & 0xFFFFFFFFFFFF0000ull) | (0xFFFFull - (unsigned long long)n));
  }
#undef HLOAD
#undef HSTORE
}

// ---------------- bitonic sort of 4096 u64 in LDS (ascending) ----------------
__device__ inline void bitonic4096(unsigned long long* s, int tid) {
  for (int k = 2; k <= 4096; k <<= 1) {
    for (int j = k >> 1; j > 0; j >>= 1) {
#pragma unroll 2
      for (int t = tid; t < 2048; t += 1024) {
        int i = ((t & ~(j - 1)) << 1) | (t & (j - 1));
        int p = i | j;
        bool up = ((i & k) == 0);
        unsigned long long a = s[i], c = s[p];
        if ((a > c) == up) { s[i] = c; s[p] = a; }
      }
      __syncthreads();
    }
  }
}

__global__ __launch_bounds__(1024) void sort_topk_kernel(
    const unsigned long long* __restrict__ in, unsigned long long* __restrict__ out,
    long in_stride, long out_stride) {
  __shared__ unsigned long long s[4096];
  const int b = blockIdx.y, q = blockIdx.x, tid = threadIdx.x;
  const unsigned long long* ip = in + (long)b * in_stride + (long)q * 4096;
#pragma unroll 4
  for (int l = tid; l < 4096; l += 1024) s[l] = ip[l];
  __syncthreads();
  bitonic4096(s, tid);
  unsigned long long* op = out + (long)b * out_stride + (long)q * 1024;
  op[tid] = s[tid];
}

__global__ __launch_bounds__(1024) void sort_final_kernel(
    const unsigned long long* __restrict__ in, int* __restrict__ sel) {
  __shared__ unsigned long long s[4096];
  const int b = blockIdx.x, tid = threadIdx.x;
  const unsigned long long* ip = in + (long)b * 4096;
#pragma unroll 4
  for (int l = tid; l < 4096; l += 1024) s[l] = ip[l];
  __syncthreads();
  bitonic4096(s, tid);
  if (tid < KPRE) sel[b * 1024 + tid] = (int)(s[tid] & 0xFFFFull);
}

// ---------------- NMS: parallel suppression-mask + single-wave scan ----------
__global__ __launch_bounds__(256) void nms_mask_kernel(
    const double* __restrict__ boxes, const int* __restrict__ sel,
    unsigned long long* __restrict__ mask) {
  __shared__ double X0[KPRE], Y0[KPRE], X1[KPRE], Y1[KPRE], AR[KPRE];
  const int ig = blockIdx.x, b = blockIdx.y, tid = threadIdx.x;
  for (int r = tid; r < KPRE; r += 256) {
    int n = sel[b * 1024 + r];
    const double* bp = boxes + ((long)b * NANCH + n) * 4;
    double x0 = bp[0], y0 = bp[1], x1 = bp[2], y1 = bp[3];
    X0[r] = x0; Y0[r] = y0; X1[r] = x1; Y1[r] = y1;
    AR[r] = (x1 - x0) * (y1 - y0);
  }
  __syncthreads();
  const int i = ig * 16 + (tid >> 4);
  const int w = tid & 15;
  if (i >= KPRE) return;
  const double xi0 = X0[i], yi0 = Y0[i], xi1 = X1[i], yi1 = Y1[i], ai = AR[i];
  unsigned long long m = 0;
#pragma unroll 8
  for (int jj = 0; jj < 64; ++jj) {
    int jo = (jj + w) & 63;
    int j = w * 64 + jo;
    if (j < KPRE && j > i) {
      double lx = fmax(xi0, X0[j]), ly = fmax(yi0, Y0[j]);
      double rx = fmin(xi1, X1[j]), ry = fmin(yi1, Y1[j]);
      double ww_ = fmax(rx - lx, 0.0);
      double hh_ = fmax(ry - ly, 0.0);
      double inter = ww_ * hh_;
      double iou = inter / (ai + AR[j] - inter + 1e-9);
      if (iou > 0.7) m |= (1ull << jo);
    }
  }
  mask[((size_t)b * 1024 + i) * 16 + w] = m;
}

__global__ __launch_bounds__(256) void nms_scan_kernel(
    const unsigned long long* __restrict__ mask, int* __restrict__ keep) {
  __shared__ unsigned long long smask[KPRE * 16];   // 125 KB
  __shared__ unsigned long long skeep[16];
  const int b = blockIdx.x, tid = threadIdx.x;
  const unsigned long long* mb = mask + (size_t)b * 1024 * 16;
  for (int l = tid; l < KPRE * 16; l += 256) smask[l] = mb[(l / 16) * 16 + (l & 15)];
  if (tid < 16) skeep[tid] = ~0ull;
  __syncthreads();
  if (tid < 64) {
    for (int i = 0; i < KPRE; ++i) {
      unsigned long long kw = skeep[i >> 6];
      if ((kw >> (i & 63)) & 1ull) {
        if (tid < 16) skeep[tid] &= ~smask[i * 16 + tid];
      }
    }
  }
  __syncthreads();
  for (int r = tid; r < KPRE; r += 256)
    keep[b * 1024 + r] = (int)((skeep[r >> 6] >> (r & 63)) & 1ull);
}

// ---------------- output: kept-first stable order, zero pad ------------------
__global__ __launch_bounds__(1024) void out_kernel(
    const double* __restrict__ boxes, const double* __restrict__ scores,
    const int* __restrict__ sel, const int* __restrict__ keep,
    float* __restrict__ out) {
  const int b = blockIdx.x, tid = threadIdx.x;
  int kv = (tid < KPRE) ? keep[b * 1024 + tid] : 0;
  unsigned long long m = __ballot(kv != 0);
  int lane = tid & 63, wid = tid >> 6;
  __shared__ int wcnt[16], woff[16], tot;
  if (lane == 0) wcnt[wid] = __popcll(m);
  __syncthreads();
  if (tid == 0) {
    int s = 0;
    for (int w2 = 0; w2 < 16; ++w2) { woff[w2] = s; s += wcnt[w2]; }
    tot = s;
  }
  __syncthreads();
  int before = __popcll(m & ((1ull << lane) - 1ull));
  int pref = woff[wid] + before;
  if (tid < KPRE) {
    int pos = kv ? pref : (tot + (tid - pref));
    if (pos < KPOST) {
      float* o = out + ((long)b * KPOST + pos) * 5;
      if (kv) {
        int n = sel[b * 1024 + tid];
        const double* bp = boxes + ((long)b * NANCH + n) * 4;
        o[0] = (float)bp[0]; o[1] = (float)bp[1];
        o[2] = (float)bp[2]; o[3] = (float)bp[3];
        o[4] = (float)scores[(long)b * NANCH + n];
      } else {
        o[0] = 0.f; o[1] = 0.f; o[2] = 0.f; o[3] = 0.f; o[4] = 0.f;
      }
    }
  }
}

extern "C" void kernel_launch(void* const* d_in, const int* in_sizes, int n_in,
                              void* d_out, int out_size, void* d_ws, size_t ws_size,
                              hipStream_t stream) {
  const float* fm     = (const float*)d_in[0];
  const float* base_w = (const float*)d_in[1];
  const float* base_b = (const float*)d_in[2];
  const float* cls_w  = (const float*)d_in[3];
  const float* cls_b  = (const float*)d_in[4];
  const float* reg_w  = (const float*)d_in[5];
  const float* reg_b  = (const float*)d_in[6];
  const int* img_h    = (const int*)d_in[7];
  const int* img_w    = (const int*)d_in[8];
  float* out          = (float*)d_out;

  if (ws_size < WS_NEEDED) return;  // visible failure rather than corruption

  char* ws = (char*)d_ws;
  double* x                 = (double*)(ws + OFF_X);
  double* scores            = (double*)(ws + OFF_SCORES);
  double* boxes             = (double*)(ws + OFF_BOXES);
  unsigned long long* keys  = (unsigned long long*)(ws + OFF_KEYS);
  unsigned long long* buf1  = (unsigned long long*)(ws + OFF_BUF1);
  unsigned long long* buf2  = (unsigned long long*)(ws + OFF_BUF2);
  int* sel                  = (int*)(ws + OFF_SEL);
  int* keep                 = (int*)(ws + OFF_KEEP);
  unsigned long long* mask  = (unsigned long long*)(ws + OFF_MASK);  // x region, dead after heads

  // pad keys (anchors 36864..65535) and buf1 (chunks 9..15) with worst key
  hipMemsetAsync(ws + OFF_KEYS, 0xFF, 4194304ull + 1048576ull, stream);

  if (ws_size >= WS_WINO_FULL) {
    double* U = (double*)(ws + WOFF_U);
    double* V = (double*)(ws + WOFF_V);
    double* M = (double*)(ws + WOFF_V + 67108864ull);
    wino_wt_kernel<<<dim3(1024), dim3(256), 0, stream>>>(base_w, U);
    for (int b = 0; b < BS; ++b) {
      wino_in_kernel<1024><<<dim3(2048), dim3(256), 0, stream>>>(fm, V, b, 0);
      wino_gemm_kernel<1024><<<dim3(8, 8, 16), dim3(256), 0, stream>>>(U, V, M);
      wino_out_kernel<1024><<<dim3(2048), dim3(256), 0, stream>>>(M, base_b, x, b, 0);
    }
  } else if (ws_size >= WS_WINO_HALF) {
    double* U = (double*)(ws + WOFF_U);
    double* V = (double*)(ws + WOFF_V);
    double* M = (double*)(ws + WOFF_V + 33554432ull);
    wino_wt_kernel<<<dim3(1024), dim3(256), 0, stream>>>(base_w, U);
    for (int b = 0; b < BS; ++b) {
      for (int t0 = 0; t0 < 1024; t0 += 512) {
        wino_in_kernel<512><<<dim3(1024), dim3(256), 0, stream>>>(fm, V, b, t0);
        wino_gemm_kernel<512><<<dim3(8, 4, 16), dim3(256), 0, stream>>>(U, V, M);
        wino_out_kernel<512><<<dim3(1024), dim3(256), 0, stream>>>(M, base_b, x, b, t0);
      }
    }
  } else {
    conv_mfma_kernel<<<dim3(8, 32, 8), dim3(256), 0, stream>>>(fm, base_w, base_b, x);
  }

  heads_mfma_kernel<<<dim3(64, 8), dim3(256), 0, stream>>>(
      x, cls_w, cls_b, reg_w, reg_b, img_h, img_w, scores, boxes, keys);
  sort_topk_kernel<<<dim3(9, 8), dim3(1024), 0, stream>>>(keys, buf1, 65536, 16384);
  sort_topk_kernel<<<dim3(4, 8), dim3(1024), 0, stream>>>(buf1, buf2, 16384, 4096);
  sort_final_kernel<<<dim3(8), dim3(1024), 0, stream>>>(buf2, sel);
  nms_mask_kernel<<<dim3(64, 8), dim3(256), 0, stream>>>(boxes, sel, mask);
  nms_scan_kernel<<<dim3(8), dim3(256), 0, stream>>>(mask, keep);
  out_kernel<<<dim3(8), dim3(1024), 0, stream>>>(boxes, scores, sel, keep, out);
}

// Round 11
// 1739.744 us; speedup vs baseline: 1.7609x; 1.0217x over previous
//
#include <hip/hip_runtime.h>
#include <math.h>

// RPNHead: conv3x3(512->512)+ReLU -> cls(9)/reg(36) 1x1 -> sigmoid/box-decode
// -> per-image exact top-1000 (by f64 score, index tie-break) -> greedy NMS
// -> [8,300,5] f32 output (kept-first stable order, zero-padded).
//
// Score/box pipeline in fp64 so top-k ordering and NMS decisions match a
// float64 numpy reference exactly (adjacent-score spacing ~5e-5..5e-8 >> f64
// noise ~1e-16; f32 would swap ranks -> wrong rows -> absmax ~1000).
//
// R2-R4: conv as implicit-GEMM on v_mfma_f64_16x16x4_f64; probe-decoded C/D
//        layout (gfx950 f64 MFMA mapping differs from CDNA2 docs).
// R5: f32 LDS, stride-80 pad, dbuf+T14, hoisted addressing. 2647us, 81%.
// R6: occupancy 2->3+ waves/SIMD + setprio. conv 2530us, MfmaUtil 85.5%.
// R7: Winograd full-image tier never ran => ws < 319.4MB.
// R8: tile-chunked Winograd T=512 (252.2MB): total 2272us. ws in [252.2,319.4).
// R9: NMS bitmask+single-wave-scan: 2272->1986us.
// R10: heads -> f64 MFMA GEMM: 1986->1777us. New top: nms_scan 109us --
//      serial chain through LDS (~260cy/iter, everything else idle).
// R11: scan chain moved to registers: lane l holds keep-word l, broadcast
//      via __shfl (~10cy/iter), mask rows prefetched 16-deep from LDS via
//      16 named registers (static idx) -- LDS latency off critical path.
//      Same mask bits + greedy order -> bit-identical keep decisions.

typedef double f64x4 __attribute__((ext_vector_type(4)));
typedef double f64x2 __attribute__((ext_vector_type(2)));

#define BS 8
#define CIN 512
#define COUT 512
#define FH 64
#define FW 64
#define NA 9
#define NPIX (FH*FW)          // 4096
#define NANCH (NPIX*NA)       // 36864
#define NPAD 65536
#define KPRE 1000
#define KPOST 300

// ---- workspace layout (bytes) ----
#define OFF_X      0ull                                   // 8*512*4096 f64 = 134217728
#define OFF_SCORES (OFF_X + 134217728ull)                 // 8*36864 f64    = 2359296
#define OFF_BOXES  (OFF_SCORES + 2359296ull)              // 8*36864*4 f64  = 9437184
#define OFF_KEYS   (OFF_BOXES + 9437184ull)               // 8*65536 u64    = 4194304
#define OFF_BUF1   (OFF_KEYS + 4194304ull)                // 8*16*1024 u64  = 1048576
#define OFF_BUF2   (OFF_BUF1 + 1048576ull)                // 8*4*1024 u64   = 262144
#define OFF_SEL    (OFF_BUF2 + 262144ull)                 // 8*1024 i32     = 32768
#define OFF_KEEP   (OFF_SEL + 32768ull)                   // 8*1024 i32     = 32768
#define WS_NEEDED  (OFF_KEEP + 32768ull)                  // 151584768
// NMS suppression-mask matrix: reuses OFF_X (x dead after heads).
#define OFF_MASK   OFF_X                                  // 8*1024*16 u64  = 1048576
// Winograd extension
#define WOFF_U        WS_NEEDED                           // 16*512*512 f64 = 33554432
#define WOFF_V        (WOFF_U + 33554432ull)
#define WS_WINO_FULL  (WOFF_V + 67108864ull + 67108864ull)  // 319356928
#define WS_WINO_HALF  (WOFF_V + 33554432ull + 33554432ull)  // 252248064

// =================== R6 direct-conv path (fallback) ==========================
#define SW_STRIDE 80
#define SW_WORDS  (36 * SW_STRIDE)
#define SI_RSTRIDE 80
#define SI_CSTRIDE 320
#define BUF_WORDS (SW_WORDS + 4 * SI_CSTRIDE)

__device__ __forceinline__ void conv_compute(
    const float* __restrict__ sWp, const float* __restrict__ sIp,
    const int* __restrict__ boff, f64x4 acc[2][4]) {
#pragma unroll
  for (int k0s = 0; k0s < 9; ++k0s) {
    double a0 = (double)sWp[k0s * 4 * SW_STRIDE];
    double a1 = (double)sWp[k0s * 4 * SW_STRIDE + 16];
    const float* bp = sIp + boff[k0s];
    double b0 = (double)bp[0];
    double b1 = (double)bp[16];
    double b2 = (double)bp[32];
    double b3 = (double)bp[48];
    acc[0][0] = __builtin_amdgcn_mfma_f64_16x16x4f64(a0, b0, acc[0][0], 0, 0, 0);
    acc[0][1] = __builtin_amdgcn_mfma_f64_16x16x4f64(a0, b1, acc[0][1], 0, 0, 0);
    acc[0][2] = __builtin_amdgcn_mfma_f64_16x16x4f64(a0, b2, acc[0][2], 0, 0, 0);
    acc[0][3] = __builtin_amdgcn_mfma_f64_16x16x4f64(a0, b3, acc[0][3], 0, 0, 0);
    acc[1][0] = __builtin_amdgcn_mfma_f64_16x16x4f64(a1, b0, acc[1][0], 0, 0, 0);
    acc[1][1] = __builtin_amdgcn_mfma_f64_16x16x4f64(a1, b1, acc[1][1], 0, 0, 0);
    acc[1][2] = __builtin_amdgcn_mfma_f64_16x16x4f64(a1, b2, acc[1][2], 0, 0, 0);
    acc[1][3] = __builtin_amdgcn_mfma_f64_16x16x4f64(a1, b3, acc[1][3], 0, 0, 0);
  }
}

__global__ __launch_bounds__(256, 3) void conv_mfma_kernel(
    const float* __restrict__ fm, const float* __restrict__ W,
    const float* __restrict__ bias, double* __restrict__ x) {
  __shared__ float sbuf[2 * BUF_WORDS];
  const int ocb = blockIdx.x, rp = blockIdx.y, b = blockIdx.z;
  const int h0 = rp * 2;
  const int oc0 = ocb * 64;
  const int tid = threadIdx.x;
  const int wid = tid >> 6, l = tid & 63;
  const int q = l >> 4, r16 = l & 15;
  const int wm = wid >> 1, wn = wid & 1;

  const int wo = tid >> 2, wseg = tid & 3;
  const float* wbase = W + (size_t)(oc0 + wo) * 4608 + wseg * 9;
  const int wlds0 = (wseg * 9) * SW_STRIDE + wo;

  const float* fmb = fm + (size_t)b * CIN * NPIX;
  int ioff[5];
  int idls[5];
  bool sact[5], lact[5];
#pragma unroll
  for (int s = 0; s < 5; ++s) {
    int li = tid + 256 * s;
    sact[s] = li < 1056;
    int li_c = sact[s] ? li : 0;
    int c = li_c / 264, rem = li_c % 264, r = rem / 66, col = rem % 66;
    int gy = h0 - 1 + r, gx = col - 1;
    lact[s] = sact[s] && gy >= 0 && gy < FH && gx >= 0 && gx < FW;
    ioff[s] = lact[s] ? (c * NPIX + gy * FW + gx) : 0;
    idls[s] = SW_WORDS + c * SI_CSTRIDE + r * SI_RSTRIDE + col;
  }

  const int apos = q * SW_STRIDE + wm * 32 + r16;
  const int ipos = SW_WORDS + wn * SI_RSTRIDE + r16;
  int boff[9];
#pragma unroll
  for (int k0s = 0; k0s < 9; ++k0s) {
    int k = k0s * 4 + q;
    int c = k / 9, t = k - 9 * c;
    int dy = t / 3, dx = t - 3 * dy;
    boff[k0s] = c * SI_CSTRIDE + dy * SI_RSTRIDE + dx;
  }

  f64x4 acc[2][4];
#pragma unroll
  for (int tm = 0; tm < 2; ++tm)
#pragma unroll
    for (int tn = 0; tn < 4; ++tn)
#pragma unroll
      for (int v = 0; v < 4; ++v) acc[tm][tn][v] = 0.0;

  float wreg[9], ireg[5];

#define LOAD_REGS(t) do {                                            \
    const int cc_ = 4 * (t);                                         \
    _Pragma("unroll")                                                \
    for (int j = 0; j < 9; ++j) wreg[j] = wbase[cc_ * 9 + j];        \
    _Pragma("unroll")                                                \
    for (int s = 0; s < 5; ++s)                                      \
      ireg[s] = lact[s] ? fmb[(size_t)(ioff[s] + cc_ * NPIX)] : 0.f; \
  } while (0)

#define WRITE_LDS(base) do {                                         \
    _Pragma("unroll")                                                \
    for (int j = 0; j < 9; ++j) (base)[wlds0 + j * SW_STRIDE] = wreg[j]; \
    _Pragma("unroll")                                                \
    for (int s = 0; s < 5; ++s)                                      \
      if (sact[s]) (base)[idls[s]] = ireg[s];                        \
  } while (0)

  float* buf0 = sbuf;
  float* buf1 = sbuf + BUF_WORDS;

  LOAD_REGS(0);
  WRITE_LDS(buf0);
  __syncthreads();

  for (int tt = 0; tt < 64; ++tt) {
    const int t1 = 2 * tt + 1;
    LOAD_REGS(t1);
    __builtin_amdgcn_s_setprio(1);
    conv_compute(buf0 + apos, buf0 + ipos, boff, acc);
    __builtin_amdgcn_s_setprio(0);
    WRITE_LDS(buf1);
    __syncthreads();
    const int t2 = (t1 + 1 < 128) ? t1 + 1 : 127;
    LOAD_REGS(t2);
    __builtin_amdgcn_s_setprio(1);
    conv_compute(buf1 + apos, buf1 + ipos, boff, acc);
    __builtin_amdgcn_s_setprio(0);
    WRITE_LDS(buf0);
    __syncthreads();
  }

  int prow[4], pcol[4];
  {
    f64x4 probe = {0.0, 0.0, 0.0, 0.0};
    double pa = (q == 0) ? (double)r16 : ((q == 1) ? 1.0 : 0.0);
    double pb = (q == 0) ? 1.0 : ((q == 1) ? (double)(16 * r16) : 0.0);
    probe = __builtin_amdgcn_mfma_f64_16x16x4f64(pa, pb, probe, 0, 0, 0);
#pragma unroll
    for (int v = 0; v < 4; ++v) {
      int val = (int)(probe[v] + 0.5);
      prow[v] = val & 15;
      pcol[v] = (val >> 4) & 15;
    }
  }

#pragma unroll
  for (int tm = 0; tm < 2; ++tm) {
#pragma unroll
    for (int v = 0; v < 4; ++v) {
      const int oc = oc0 + wm * 32 + tm * 16 + prow[v];
      const double bv = (double)bias[oc];
      const int h = h0 + wn;
#pragma unroll
      for (int tn = 0; tn < 4; ++tn) {
        const int w = tn * 16 + pcol[v];
        double val = acc[tm][tn][v] + bv;
        val = val > 0.0 ? val : 0.0;
        x[(size_t)(b * COUT + oc) * NPIX + h * FW + w] = val;
      }
    }
  }
#undef LOAD_REGS
#undef WRITE_LDS
}

// =================== Winograd F(2x2,3x3) path (tile-chunked) =================
__global__ __launch_bounds__(256) void wino_wt_kernel(
    const float* __restrict__ W, double* __restrict__ U) {
  const int id = blockIdx.x * 256 + threadIdx.x;   // 262144
  const int oc = id >> 9, c = id & 511;
  const float* g = W + (size_t)(oc * CIN + c) * 9;
  double g0[3], g1[3], g2[3];
#pragma unroll
  for (int j = 0; j < 3; ++j) {
    g0[j] = (double)g[j];
    g1[j] = (double)g[3 + j];
    g2[j] = (double)g[6 + j];
  }
  double T[4][3];
#pragma unroll
  for (int j = 0; j < 3; ++j) {
    T[0][j] = g0[j];
    T[1][j] = 0.5 * (g0[j] + g1[j] + g2[j]);
    T[2][j] = 0.5 * (g0[j] - g1[j] + g2[j]);
    T[3][j] = g2[j];
  }
  double* Ub = U + (size_t)c * 512 + oc;   // + pos*262144
#pragma unroll
  for (int xi = 0; xi < 4; ++xi) {
    double u0 = T[xi][0];
    double u1 = 0.5 * (T[xi][0] + T[xi][1] + T[xi][2]);
    double u2 = 0.5 * (T[xi][0] - T[xi][1] + T[xi][2]);
    double u3 = T[xi][2];
    Ub[(size_t)(xi * 4 + 0) * 262144] = u0;
    Ub[(size_t)(xi * 4 + 1) * 262144] = u1;
    Ub[(size_t)(xi * 4 + 2) * 262144] = u2;
    Ub[(size_t)(xi * 4 + 3) * 262144] = u3;
  }
}

template <int T>
__global__ __launch_bounds__(256) void wino_in_kernel(
    const float* __restrict__ fm, double* __restrict__ V, int b, int t0) {
  const int id = blockIdx.x * 256 + threadIdx.x;   // 512*T
  const int c = id / T, rem = id % T;
  const int tyx = t0 + rem;
  const int ty = tyx >> 5, tx = tyx & 31;
  const float* src = fm + (size_t)(b * CIN + c) * NPIX;
  const int y0 = 2 * ty - 1, x0 = 2 * tx - 1;
  double d[4][4];
#pragma unroll
  for (int r = 0; r < 4; ++r) {
    int y = y0 + r;
#pragma unroll
    for (int s = 0; s < 4; ++s) {
      int xx = x0 + s;
      d[r][s] = (y >= 0 && y < FH && xx >= 0 && xx < FW)
                    ? (double)src[y * FW + xx] : 0.0;
    }
  }
  double Z[4][4];
#pragma unroll
  for (int s = 0; s < 4; ++s) {
    Z[0][s] = d[0][s] - d[2][s];
    Z[1][s] = d[1][s] + d[2][s];
    Z[2][s] = d[2][s] - d[1][s];
    Z[3][s] = d[1][s] - d[3][s];
  }
  double* Vb = V + (size_t)c * T + rem;   // + pos*512*T
#pragma unroll
  for (int xi = 0; xi < 4; ++xi) {
    double v0 = Z[xi][0] - Z[xi][2];
    double v1 = Z[xi][1] + Z[xi][2];
    double v2 = Z[xi][2] - Z[xi][1];
    double v3 = Z[xi][1] - Z[xi][3];
    Vb[(size_t)(xi * 4 + 0) * 512 * T] = v0;
    Vb[(size_t)(xi * 4 + 1) * 512 * T] = v1;
    Vb[(size_t)(xi * 4 + 2) * 512 * T] = v2;
    Vb[(size_t)(xi * 4 + 3) * 512 * T] = v3;
  }
}

#define WSU_STRIDE 72
#define WSV_STRIDE 136
#define WSU_WORDS  (8 * WSU_STRIDE)              // 576
#define WBUF_WORDS (WSU_WORDS + 8 * WSV_STRIDE)  // 1664 f64 = 13312 B

__device__ __forceinline__ void wino_compute(
    const double* __restrict__ sA, const double* __restrict__ sB,
    f64x4 acc[2][4]) {
#pragma unroll
  for (int kg = 0; kg < 2; ++kg) {
    double a0 = sA[kg * 4 * WSU_STRIDE];
    double a1 = sA[kg * 4 * WSU_STRIDE + 16];
    const double* bp = sB + kg * 4 * WSV_STRIDE;
    double b0 = bp[0];
    double b1 = bp[16];
    double b2 = bp[32];
    double b3 = bp[48];
    acc[0][0] = __builtin_amdgcn_mfma_f64_16x16x4f64(a0, b0, acc[0][0], 0, 0, 0);
    acc[0][1] = __builtin_amdgcn_mfma_f64_16x16x4f64(a0, b1, acc[0][1], 0, 0, 0);
    acc[0][2] = __builtin_amdgcn_mfma_f64_16x16x4f64(a0, b2, acc[0][2], 0, 0, 0);
    acc[0][3] = __builtin_amdgcn_mfma_f64_16x16x4f64(a0, b3, acc[0][3], 0, 0, 0);
    acc[1][0] = __builtin_amdgcn_mfma_f64_16x16x4f64(a1, b0, acc[1][0], 0, 0, 0);
    acc[1][1] = __builtin_amdgcn_mfma_f64_16x16x4f64(a1, b1, acc[1][1], 0, 0, 0);
    acc[1][2] = __builtin_amdgcn_mfma_f64_16x16x4f64(a1, b2, acc[1][2], 0, 0, 0);
    acc[1][3] = __builtin_amdgcn_mfma_f64_16x16x4f64(a1, b3, acc[1][3], 0, 0, 0);
  }
}

template <int T>
__global__ __launch_bounds__(256, 3) void wino_gemm_kernel(
    const double* __restrict__ U, const double* __restrict__ V,
    double* __restrict__ M) {
  __shared__ double sbuf[2 * WBUF_WORDS];
  const int ocb = blockIdx.x, tb = blockIdx.y, pos = blockIdx.z;
  const int oc0 = ocb * 64, t0 = tb * 128;
  const int tid = threadIdx.x;
  const int wid = tid >> 6, l = tid & 63;
  const int q = l >> 4, r16 = l & 15;
  const int wm = wid >> 1, wn = wid & 1;   // 2(M) x 2(N) waves

  const int ka = tid >> 5;                 // 0..7
  const int oc2 = (tid & 31) * 2;          // A: 2 f64/thread
  const int t4 = (tid & 31) * 4;           // B: 4 f64/thread
  const double* uSrc = U + (size_t)pos * 262144 + (size_t)ka * 512 + oc0 + oc2;
  const double* vSrc = V + (size_t)pos * 512 * T + (size_t)ka * T + t0 + t4;
  const int ua_lds = ka * WSU_STRIDE + oc2;
  const int vb_lds = WSU_WORDS + ka * WSV_STRIDE + t4;

  const int apos = q * WSU_STRIDE + wm * 32 + r16;
  const int bpos = WSU_WORDS + q * WSV_STRIDE + wn * 64 + r16;

  f64x4 acc[2][4];
#pragma unroll
  for (int tm = 0; tm < 2; ++tm)
#pragma unroll
    for (int tn = 0; tn < 4; ++tn)
#pragma unroll
      for (int v = 0; v < 4; ++v) acc[tm][tn][v] = 0.0;

  f64x2 ra, rb0, rb1;

#define WLOAD(t) do {                                                  \
    const size_t cc_ = 8 * (size_t)(t);                                \
    ra  = *(const f64x2*)(uSrc + cc_ * 512);                           \
    rb0 = *(const f64x2*)(vSrc + cc_ * T);                             \
    rb1 = *(const f64x2*)(vSrc + cc_ * T + 2);                         \
  } while (0)

#define WSTORE(base) do {                                              \
    (base)[ua_lds] = ra[0]; (base)[ua_lds + 1] = ra[1];                \
    (base)[vb_lds] = rb0[0]; (base)[vb_lds + 1] = rb0[1];              \
    (base)[vb_lds + 2] = rb1[0]; (base)[vb_lds + 3] = rb1[1];          \
  } while (0)

  double* buf0 = sbuf;
  double* buf1 = sbuf + WBUF_WORDS;

  WLOAD(0);
  WSTORE(buf0);
  __syncthreads();

  for (int tt = 0; tt < 32; ++tt) {
    const int t1 = 2 * tt + 1;
    WLOAD(t1);
    __builtin_amdgcn_s_setprio(1);
    wino_compute(buf0 + apos, buf0 + bpos, acc);
    __builtin_amdgcn_s_setprio(0);
    WSTORE(buf1);
    __syncthreads();
    const int t2 = (t1 + 1 < 64) ? t1 + 1 : 63;
    WLOAD(t2);
    __builtin_amdgcn_s_setprio(1);
    wino_compute(buf1 + apos, buf1 + bpos, acc);
    __builtin_amdgcn_s_setprio(0);
    WSTORE(buf0);
    __syncthreads();
  }

  int prow[4], pcol[4];
  {
    f64x4 probe = {0.0, 0.0, 0.0, 0.0};
    double pa = (q == 0) ? (double)r16 : ((q == 1) ? 1.0 : 0.0);
    double pb = (q == 0) ? 1.0 : ((q == 1) ? (double)(16 * r16) : 0.0);
    probe = __builtin_amdgcn_mfma_f64_16x16x4f64(pa, pb, probe, 0, 0, 0);
#pragma unroll
    for (int v = 0; v < 4; ++v) {
      int val = (int)(probe[v] + 0.5);
      prow[v] = val & 15;
      pcol[v] = (val >> 4) & 15;
    }
  }

#pragma unroll
  for (int tm = 0; tm < 2; ++tm) {
#pragma unroll
    for (int v = 0; v < 4; ++v) {
      const int oc = oc0 + wm * 32 + tm * 16 + prow[v];
#pragma unroll
      for (int tn = 0; tn < 4; ++tn) {
        const int col = wn * 64 + tn * 16 + pcol[v];
        M[(size_t)pos * 512 * T + (size_t)oc * T + t0 + col] = acc[tm][tn][v];
      }
    }
  }
#undef WLOAD
#undef WSTORE
}

template <int T>
__global__ __launch_bounds__(256) void wino_out_kernel(
    const double* __restrict__ M, const float* __restrict__ bias,
    double* __restrict__ x, int b, int t0) {
  const int id = blockIdx.x * 256 + threadIdx.x;   // 512*T
  const int oc = id / T, rem = id % T;
  const int tyx = t0 + rem;
  const int ty = tyx >> 5, tx = tyx & 31;
  double m[4][4];
#pragma unroll
  for (int xi = 0; xi < 4; ++xi)
#pragma unroll
    for (int nu = 0; nu < 4; ++nu)
      m[xi][nu] = M[(size_t)(xi * 4 + nu) * 512 * T + (size_t)oc * T + rem];
  double P[2][4];
#pragma unroll
  for (int nu = 0; nu < 4; ++nu) {
    P[0][nu] = m[0][nu] + m[1][nu] + m[2][nu];
    P[1][nu] = m[1][nu] - m[2][nu] - m[3][nu];
  }
  const double bv = (double)bias[oc];
  double* xb = x + (size_t)(b * COUT + oc) * NPIX + (2 * ty) * FW + 2 * tx;
#pragma unroll
  for (int i = 0; i < 2; ++i) {
    double y0 = P[i][0] + P[i][1] + P[i][2] + bv;
    double y1 = P[i][1] - P[i][2] - P[i][3] + bv;
    y0 = y0 > 0.0 ? y0 : 0.0;
    y1 = y1 > 0.0 ? y1 : 0.0;
    xb[i * FW] = y0;
    xb[i * FW + 1] = y1;
  }
}

// ---------------- heads: f64 MFMA GEMM (48oc x 64px tiles) + decode ----------
#define HX_STRIDE 72                       // sx [16][72]
#define HW_STRIDE 52                       // sw [16][52]
#define HSX_WORDS (16 * HX_STRIDE)         // 1152
#define HBUF_WORDS (HSX_WORDS + 16 * HW_STRIDE)  // 1984

__device__ __forceinline__ void heads_compute(
    const double* __restrict__ sA, const double* __restrict__ sB,
    f64x4 acc[3]) {
#pragma unroll
  for (int k0s = 0; k0s < 4; ++k0s) {
    double a0 = sA[k0s * 4 * HW_STRIDE];
    double a1 = sA[k0s * 4 * HW_STRIDE + 16];
    double a2 = sA[k0s * 4 * HW_STRIDE + 32];
    double b0 = sB[k0s * 4 * HX_STRIDE];
    acc[0] = __builtin_amdgcn_mfma_f64_16x16x4f64(a0, b0, acc[0], 0, 0, 0);
    acc[1] = __builtin_amdgcn_mfma_f64_16x16x4f64(a1, b0, acc[1], 0, 0, 0);
    acc[2] = __builtin_amdgcn_mfma_f64_16x16x4f64(a2, b0, acc[2], 0, 0, 0);
  }
}

__global__ __launch_bounds__(256) void heads_mfma_kernel(
    const double* __restrict__ x, const float* __restrict__ cls_w,
    const float* __restrict__ cls_b, const float* __restrict__ reg_w,
    const float* __restrict__ reg_b, const int* __restrict__ img_h,
    const int* __restrict__ img_w, double* __restrict__ scores,
    double* __restrict__ boxes, unsigned long long* __restrict__ keys) {
  __shared__ double sh[2 * HBUF_WORDS];    // dbuf staging; logits reuse (3240<3968)
  const int pxb = blockIdx.x, b = blockIdx.y;
  const int tid = threadIdx.x;
  const int wid = tid >> 6, l = tid & 63;
  const int q = l >> 4, r16 = l & 15;
  const int wn = wid;                      // wave's 16-px slice

  const double* xbase = x + (size_t)b * CIN * NPIX + pxb * 64;
  int sxk[4], sxp[4];
#pragma unroll
  for (int s = 0; s < 4; ++s) {
    int i = tid + 256 * s;
    sxk[s] = i >> 6; sxp[s] = i & 63;
  }
  int swk[3], swo[3];
#pragma unroll
  for (int s = 0; s < 3; ++s) {
    int i = tid + 256 * s;                 // < 768 always
    swk[s] = i / 48; swo[s] = i % 48;
  }

  const int aposh = HSX_WORDS + q * HW_STRIDE + r16;  // + k0s*4*HW + mt*16
  const int bposh = q * HX_STRIDE + wn * 16 + r16;    // + k0s*4*HX

  f64x4 acc[3];
#pragma unroll
  for (int mt = 0; mt < 3; ++mt)
#pragma unroll
    for (int v = 0; v < 4; ++v) acc[mt][v] = 0.0;

  double xr[4], wr[3];

#define HLOAD(t) do {                                                    \
    const int cc_ = 16 * (t);                                            \
    _Pragma("unroll")                                                    \
    for (int s = 0; s < 4; ++s)                                          \
      xr[s] = xbase[(size_t)(cc_ + sxk[s]) * NPIX + sxp[s]];             \
    _Pragma("unroll")                                                    \
    for (int s = 0; s < 3; ++s) {                                        \
      int o = swo[s], k = cc_ + swk[s];                                  \
      wr[s] = (o < 9) ? (double)cls_w[o * CIN + k]                       \
            : (o < 45) ? (double)reg_w[(o - 9) * CIN + k] : 0.0;         \
    }                                                                    \
  } while (0)

#define HSTORE(base) do {                                                \
    _Pragma("unroll")                                                    \
    for (int s = 0; s < 4; ++s) (base)[sxk[s] * HX_STRIDE + sxp[s]] = xr[s]; \
    _Pragma("unroll")                                                    \
    for (int s = 0; s < 3; ++s)                                          \
      (base)[HSX_WORDS + swk[s] * HW_STRIDE + swo[s]] = wr[s];           \
  } while (0)

  double* buf0 = sh;
  double* buf1 = sh + HBUF_WORDS;

  HLOAD(0);
  HSTORE(buf0);
  __syncthreads();

  for (int tt = 0; tt < 16; ++tt) {
    const int t1 = 2 * tt + 1;
    HLOAD(t1);
    __builtin_amdgcn_s_setprio(1);
    heads_compute(buf0 + aposh, buf0 + bposh, acc);
    __builtin_amdgcn_s_setprio(0);
    HSTORE(buf1);
    __syncthreads();
    const int t2 = (t1 + 1 < 32) ? t1 + 1 : 31;
    HLOAD(t2);
    __builtin_amdgcn_s_setprio(1);
    heads_compute(buf1 + aposh, buf1 + bposh, acc);
    __builtin_amdgcn_s_setprio(0);
    HSTORE(buf0);
    __syncthreads();
  }

  int prow[4], pcol[4];
  {
    f64x4 probe = {0.0, 0.0, 0.0, 0.0};
    double pa = (q == 0) ? (double)r16 : ((q == 1) ? 1.0 : 0.0);
    double pb = (q == 0) ? 1.0 : ((q == 1) ? (double)(16 * r16) : 0.0);
    probe = __builtin_amdgcn_mfma_f64_16x16x4f64(pa, pb, probe, 0, 0, 0);
#pragma unroll
    for (int v = 0; v < 4; ++v) {
      int val = (int)(probe[v] + 0.5);
      prow[v] = val & 15;
      pcol[v] = (val >> 4) & 15;
    }
  }

  double* slog = sh;
#pragma unroll
  for (int mt = 0; mt < 3; ++mt) {
#pragma unroll
    for (int v = 0; v < 4; ++v) {
      const int o = mt * 16 + prow[v];
      if (o < 45) {
        double bv = (o < 9) ? (double)cls_b[o] : (double)reg_b[o - 9];
        slog[o * HX_STRIDE + wn * 16 + pcol[v]] = acc[mt][v] + bv;
      }
    }
  }
  __syncthreads();

  const double ih = (double)img_h[0], iw = (double)img_w[0];
  const double sth = ih / (double)FH, stw = iw / (double)FW;
  const double ratios[3] = {0.5, 1.0, 2.0};
  const double sizes[3] = {128.0, 256.0, 512.0};

  for (int it = tid; it < 576; it += 256) {
    int px = it / 9, a = it % 9;
    int p = pxb * 64 + px;
    int hh = p >> 6, ww = p & 63;
    double z = slog[a * HX_STRIDE + px];
    double score = 1.0 / (1.0 + exp(-z));
    double d0 = slog[(9 + a * 4 + 0) * HX_STRIDE + px];
    double d1 = slog[(9 + a * 4 + 1) * HX_STRIDE + px];
    double d2 = slog[(9 + a * 4 + 2) * HX_STRIDE + px];
    double d3 = slog[(9 + a * 4 + 3) * HX_STRIDE + px];
    double ratio = ratios[a / 3], size = sizes[a % 3];
    double hr = sqrt(ratio), wr_ = 1.0 / hr;
    double wsz = wr_ * size, hsz = hr * size;
    double sxc = (double)ww * stw, syc = (double)hh * sth;
    double ax0 = sxc - wsz * 0.5, ax1 = sxc + wsz * 0.5;
    double ay0 = syc - hsz * 0.5, ay1 = syc + hsz * 0.5;
    double aw = ax1 - ax0, ah = ay1 - ay0;
    double acx = ax0 + 0.5 * aw, acy = ay0 + 0.5 * ah;
    double pcx = d0 * aw + acx, pcy = d1 * ah + acy;
    double pw = exp(d2) * aw, ph = exp(d3) * ah;
    double bx0 = pcx - 0.5 * pw, by0 = pcy - 0.5 * ph;
    double bx1 = pcx + 0.5 * pw, by1 = pcy + 0.5 * ph;
    bx0 = fmin(fmax(bx0, 0.0), iw); bx1 = fmin(fmax(bx1, 0.0), iw);
    by0 = fmin(fmax(by0, 0.0), ih); by1 = fmin(fmax(by1, 0.0), ih);
    long n = (long)p * 9 + a;
    long base = (long)b * NANCH + n;
    boxes[base * 4 + 0] = bx0; boxes[base * 4 + 1] = by0;
    boxes[base * 4 + 2] = bx1; boxes[base * 4 + 3] = by1;
    scores[base] = score;
    unsigned long long bits = (unsigned long long)__double_as_longlong(score);
    keys[(long)b * NPAD + n] =
        ~((bits & 0xFFFFFFFFFFFF0000ull) | (0xFFFFull - (unsigned long long)n));
  }
#undef HLOAD
#undef HSTORE
}

// ---------------- bitonic sort of 4096 u64 in LDS (ascending) ----------------
__device__ inline void bitonic4096(unsigned long long* s, int tid) {
  for (int k = 2; k <= 4096; k <<= 1) {
    for (int j = k >> 1; j > 0; j >>= 1) {
#pragma unroll 2
      for (int t = tid; t < 2048; t += 1024) {
        int i = ((t & ~(j - 1)) << 1) | (t & (j - 1));
        int p = i | j;
        bool up = ((i & k) == 0);
        unsigned long long a = s[i], c = s[p];
        if ((a > c) == up) { s[i] = c; s[p] = a; }
      }
      __syncthreads();
    }
  }
}

__global__ __launch_bounds__(1024) void sort_topk_kernel(
    const unsigned long long* __restrict__ in, unsigned long long* __restrict__ out,
    long in_stride, long out_stride) {
  __shared__ unsigned long long s[4096];
  const int b = blockIdx.y, q = blockIdx.x, tid = threadIdx.x;
  const unsigned long long* ip = in + (long)b * in_stride + (long)q * 4096;
#pragma unroll 4
  for (int l = tid; l < 4096; l += 1024) s[l] = ip[l];
  __syncthreads();
  bitonic4096(s, tid);
  unsigned long long* op = out + (long)b * out_stride + (long)q * 1024;
  op[tid] = s[tid];
}

__global__ __launch_bounds__(1024) void sort_final_kernel(
    const unsigned long long* __restrict__ in, int* __restrict__ sel) {
  __shared__ unsigned long long s[4096];
  const int b = blockIdx.x, tid = threadIdx.x;
  const unsigned long long* ip = in + (long)b * 4096;
#pragma unroll 4
  for (int l = tid; l < 4096; l += 1024) s[l] = ip[l];
  __syncthreads();
  bitonic4096(s, tid);
  if (tid < KPRE) sel[b * 1024 + tid] = (int)(s[tid] & 0xFFFFull);
}

// ---------------- NMS: parallel suppression-mask + register-chain scan -------
__global__ __launch_bounds__(256) void nms_mask_kernel(
    const double* __restrict__ boxes, const int* __restrict__ sel,
    unsigned long long* __restrict__ mask) {
  __shared__ double X0[KPRE], Y0[KPRE], X1[KPRE], Y1[KPRE], AR[KPRE];
  const int ig = blockIdx.x, b = blockIdx.y, tid = threadIdx.x;
  for (int r = tid; r < KPRE; r += 256) {
    int n = sel[b * 1024 + r];
    const double* bp = boxes + ((long)b * NANCH + n) * 4;
    double x0 = bp[0], y0 = bp[1], x1 = bp[2], y1 = bp[3];
    X0[r] = x0; Y0[r] = y0; X1[r] = x1; Y1[r] = y1;
    AR[r] = (x1 - x0) * (y1 - y0);
  }
  __syncthreads();
  const int i = ig * 16 + (tid >> 4);
  const int w = tid & 15;
  if (i >= KPRE) return;
  const double xi0 = X0[i], yi0 = Y0[i], xi1 = X1[i], yi1 = Y1[i], ai = AR[i];
  unsigned long long m = 0;
#pragma unroll 8
  for (int jj = 0; jj < 64; ++jj) {
    int jo = (jj + w) & 63;
    int j = w * 64 + jo;
    if (j < KPRE && j > i) {
      double lx = fmax(xi0, X0[j]), ly = fmax(yi0, Y0[j]);
      double rx = fmin(xi1, X1[j]), ry = fmin(yi1, Y1[j]);
      double ww_ = fmax(rx - lx, 0.0);
      double hh_ = fmax(ry - ly, 0.0);
      double inter = ww_ * hh_;
      double iou = inter / (ai + AR[j] - inter + 1e-9);
      if (iou > 0.7) m |= (1ull << jo);
    }
  }
  mask[((size_t)b * 1024 + i) * 16 + w] = m;
}

// one block per image. Keep-state lives in REGISTERS (lane l holds word l,
// broadcast via __shfl ~10cy/iter, vs ~260cy/iter through LDS in R9's scan).
// Mask rows prefetched 16-deep from LDS via 16 NAMED registers (static idx;
// runtime-indexed arrays spill to scratch). Rows 1000..1023 of smask are
// uninitialized but guarded by (ii < KPRE) -> never applied -> deterministic.
__global__ __launch_bounds__(256) void nms_scan_kernel(
    const unsigned long long* __restrict__ mask, int* __restrict__ keep) {
  __shared__ unsigned long long smask[16384];   // 1024 rows x 16 words, 128 KB
  __shared__ unsigned long long skeep[16];
  const int b = blockIdx.x, tid = threadIdx.x;
  const unsigned long long* mb = mask + (size_t)b * 1024 * 16;
  for (int l = tid; l < KPRE * 16; l += 256) smask[l] = mb[l];
  __syncthreads();
  if (tid < 64) {
    const int lane16 = tid & 15;   // all 64 lanes mirror lanes 0..15 (LDS broadcast)
    unsigned long long mykeep = ~0ull;
    unsigned long long p0, p1, p2, p3, p4, p5, p6, p7,
                       p8, p9, p10, p11, p12, p13, p14, p15;
    p0  = smask[0 * 16 + lane16];  p1  = smask[1 * 16 + lane16];
    p2  = smask[2 * 16 + lane16];  p3  = smask[3 * 16 + lane16];
    p4  = smask[4 * 16 + lane16];  p5  = smask[5 * 16 + lane16];
    p6  = smask[6 * 16 + lane16];  p7  = smask[7 * 16 + lane16];
    p8  = smask[8 * 16 + lane16];  p9  = smask[9 * 16 + lane16];
    p10 = smask[10 * 16 + lane16]; p11 = smask[11 * 16 + lane16];
    p12 = smask[12 * 16 + lane16]; p13 = smask[13 * 16 + lane16];
    p14 = smask[14 * 16 + lane16]; p15 = smask[15 * 16 + lane16];
#define NMS_STEP(j) do {                                                   \
      const int ii = i + (j);                                              \
      unsigned long long kw = __shfl(mykeep, ii >> 6);                     \
      bool on = (ii < KPRE) && ((kw >> (ii & 63)) & 1ull);                 \
      mykeep &= ~(on ? p##j : 0ull);                                       \
      p##j = smask[(ii + 16) * 16 + lane16];                               \
    } while (0)
    for (int i = 0; i < 1008; i += 16) {   // 63 x 16 = 1008 steps, ii<1000 guarded
      NMS_STEP(0);  NMS_STEP(1);  NMS_STEP(2);  NMS_STEP(3);
      NMS_STEP(4);  NMS_STEP(5);  NMS_STEP(6);  NMS_STEP(7);
      NMS_STEP(8);  NMS_STEP(9);  NMS_STEP(10); NMS_STEP(11);
      NMS_STEP(12); NMS_STEP(13); NMS_STEP(14); NMS_STEP(15);
    }
#undef NMS_STEP
    if (tid < 16) skeep[tid] = mykeep;
  }
  __syncthreads();
  for (int r = tid; r < KPRE; r += 256)
    keep[b * 1024 + r] = (int)((skeep[r >> 6] >> (r & 63)) & 1ull);
}

// ---------------- output: kept-first stable order, zero pad ------------------
__global__ __launch_bounds__(1024) void out_kernel(
    const double* __restrict__ boxes, const double* __restrict__ scores,
    const int* __restrict__ sel, const int* __restrict__ keep,
    float* __restrict__ out) {
  const int b = blockIdx.x, tid = threadIdx.x;
  int kv = (tid < KPRE) ? keep[b * 1024 + tid] : 0;
  unsigned long long m = __ballot(kv != 0);
  int lane = tid & 63, wid = tid >> 6;
  __shared__ int wcnt[16], woff[16], tot;
  if (lane == 0) wcnt[wid] = __popcll(m);
  __syncthreads();
  if (tid == 0) {
    int s = 0;
    for (int w2 = 0; w2 < 16; ++w2) { woff[w2] = s; s += wcnt[w2]; }
    tot = s;
  }
  __syncthreads();
  int before = __popcll(m & ((1ull << lane) - 1ull));
  int pref = woff[wid] + before;
  if (tid < KPRE) {
    int pos = kv ? pref : (tot + (tid - pref));
    if (pos < KPOST) {
      float* o = out + ((long)b * KPOST + pos) * 5;
      if (kv) {
        int n = sel[b * 1024 + tid];
        const double* bp = boxes + ((long)b * NANCH + n) * 4;
        o[0] = (float)bp[0]; o[1] = (float)bp[1];
        o[2] = (float)bp[2]; o[3] = (float)bp[3];
        o[4] = (float)scores[(long)b * NANCH + n];
      } else {
        o[0] = 0.f; o[1] = 0.f; o[2] = 0.f; o[3] = 0.f; o[4] = 0.f;
      }
    }
  }
}

extern "C" void kernel_launch(void* const* d_in, const int* in_sizes, int n_in,
                              void* d_out, int out_size, void* d_ws, size_t ws_size,
                              hipStream_t stream) {
  const float* fm     = (const float*)d_in[0];
  const float* base_w = (const float*)d_in[1];
  const float* base_b = (const float*)d_in[2];
  const float* cls_w  = (const float*)d_in[3];
  const float* cls_b  = (const float*)d_in[4];
  const float* reg_w  = (const float*)d_in[5];
  const float* reg_b  = (const float*)d_in[6];
  const int* img_h    = (const int*)d_in[7];
  const int* img_w    = (const int*)d_in[8];
  float* out          = (float*)d_out;

  if (ws_size < WS_NEEDED) return;  // visible failure rather than corruption

  char* ws = (char*)d_ws;
  double* x                 = (double*)(ws + OFF_X);
  double* scores            = (double*)(ws + OFF_SCORES);
  double* boxes             = (double*)(ws + OFF_BOXES);
  unsigned long long* keys  = (unsigned long long*)(ws + OFF_KEYS);
  unsigned long long* buf1  = (unsigned long long*)(ws + OFF_BUF1);
  unsigned long long* buf2  = (unsigned long long*)(ws + OFF_BUF2);
  int* sel                  = (int*)(ws + OFF_SEL);
  int* keep                 = (int*)(ws + OFF_KEEP);
  unsigned long long* mask  = (unsigned long long*)(ws + OFF_MASK);  // x region, dead after heads

  // pad keys (anchors 36864..65535) and buf1 (chunks 9..15) with worst key
  hipMemsetAsync(ws + OFF_KEYS, 0xFF, 4194304ull + 1048576ull, stream);

  if (ws_size >= WS_WINO_FULL) {
    double* U = (double*)(ws + WOFF_U);
    double* V = (double*)(ws + WOFF_V);
    double* M = (double*)(ws + WOFF_V + 67108864ull);
    wino_wt_kernel<<<dim3(1024), dim3(256), 0, stream>>>(base_w, U);
    for (int b = 0; b < BS; ++b) {
      wino_in_kernel<1024><<<dim3(2048), dim3(256), 0, stream>>>(fm, V, b, 0);
      wino_gemm_kernel<1024><<<dim3(8, 8, 16), dim3(256), 0, stream>>>(U, V, M);
      wino_out_kernel<1024><<<dim3(2048), dim3(256), 0, stream>>>(M, base_b, x, b, 0);
    }
  } else if (ws_size >= WS_WINO_HALF) {
    double* U = (double*)(ws + WOFF_U);
    double* V = (double*)(ws + WOFF_V);
    double* M = (double*)(ws + WOFF_V + 33554432ull);
    wino_wt_kernel<<<dim3(1024), dim3(256), 0, stream>>>(base_w, U);
    for (int b = 0; b < BS; ++b) {
      for (int t0 = 0; t0 < 1024; t0 += 512) {
        wino_in_kernel<512><<<dim3(1024), dim3(256), 0, stream>>>(fm, V, b, t0);
        wino_gemm_kernel<512><<<dim3(8, 4, 16), dim3(256), 0, stream>>>(U, V, M);
        wino_out_kernel<512><<<dim3(1024), dim3(256), 0, stream>>>(M, base_b, x, b, t0);
      }
    }
  } else {
    conv_mfma_kernel<<<dim3(8, 32, 8), dim3(256), 0, stream>>>(fm, base_w, base_b, x);
  }

  heads_mfma_kernel<<<dim3(64, 8), dim3(256), 0, stream>>>(
      x, cls_w, cls_b, reg_w, reg_b, img_h, img_w, scores, boxes, keys);
  sort_topk_kernel<<<dim3(9, 8), dim3(1024), 0, stream>>>(keys, buf1, 65536, 16384);
  sort_topk_kernel<<<dim3(4, 8), dim3(1024), 0, stream>>>(buf1, buf2, 16384, 4096);
  sort_final_kernel<<<dim3(8), dim3(1024), 0, stream>>>(buf2, sel);
  nms_mask_kernel<<<dim3(64, 8), dim3(256), 0, stream>>>(boxes, sel, mask);
  nms_scan_kernel<<<dim3(8), dim3(256), 0, stream>>>(mask, keep);
  out_kernel<<<dim3(8), dim3(1024), 0, stream>>>(boxes, scores, sel, keep, out);
}